// Round 4
// baseline (563.582 us; speedup 1.0000x reference)
//
#include <hip/hip_runtime.h>
#include <hip/hip_bf16.h>
#include <math.h>

#define N_NODES    100000
#define N_EDGES    1600000
#define NUM_GRAPHS 512
#define D2 50
#define D3 15
#define D5 10
#define NCLS 6
#define BN_EPS 1e-5f

#define NBLK1 ((N_NODES + 1023) / 1024)   // 98 scan blocks

// padded-transposed bf16 weight buffer layout (elements)
// ew1T [64 m][40 k]  : k0-2 x_row, k3 bias, k4-6 x_col, k8-10 ea
// ew2T [16 m][72 k]  : k0-49 h1, k50 bias
// nw1T [64 m][40 k]  : k0-14 e2, k16-18 x_col, k19 bias
// nw2T [16 m][72 k]  : k0-49 h2, k50 bias
#define W_EW1T 0
#define W_EW2T 2560
#define W_NW1T 3712
#define W_NW2T 6272
#define W_TOTAL 7680   // padded to 960 * 16B

typedef __attribute__((ext_vector_type(8))) short short8;
typedef __attribute__((ext_vector_type(4))) float float4_;

__device__ __forceinline__ unsigned short f2bf(float f) {
    __hip_bfloat16 h = __float2bfloat16(f);
    union { __hip_bfloat16 h; unsigned short u; } c; c.h = h; return c.u;
}
__device__ __forceinline__ float bf2f(unsigned short u) {
    union { __hip_bfloat16 h; unsigned short u; } c; c.u = u;
    return __bfloat162float(c.h);
}
__device__ __forceinline__ unsigned int pkbf(float a, float b) {
    return (unsigned int)f2bf(a) | ((unsigned int)f2bf(b) << 16);
}

// ---------- weight prep: padded/transposed bf16 hi+lo split ----------
__global__ __launch_bounds__(256) void wprep_kernel(
    const float* __restrict__ ew1, const float* __restrict__ eb1,
    const float* __restrict__ ew2, const float* __restrict__ eb2,
    const float* __restrict__ nw1, const float* __restrict__ nb1,
    const float* __restrict__ nw2, const float* __restrict__ nb2,
    unsigned short* __restrict__ wh, unsigned short* __restrict__ wl)
{
    for (int i = threadIdx.x; i < W_TOTAL; i += 256) {
        float v = 0.0f;
        if (i < W_EW2T) {
            int m = i / 40, k = i % 40;
            if (m < 50) {
                if (k < 3)                 v = ew1[k * 50 + m];
                else if (k == 3)           v = eb1[m];
                else if (k >= 4 && k < 7)  v = ew1[(k - 1) * 50 + m];
                else if (k >= 8 && k < 11) v = ew1[(k - 2) * 50 + m];
            }
        } else if (i < W_NW1T) {
            int j = i - W_EW2T; int m = j / 72, k = j % 72;
            if (m < 15) { if (k < 50) v = ew2[k * 15 + m]; else if (k == 50) v = eb2[m]; }
        } else if (i < W_NW2T) {
            int j = i - W_NW1T; int m = j / 40, k = j % 40;
            if (m < 50) {
                if (k < 15)                  v = nw1[(3 + k) * 50 + m];
                else if (k >= 16 && k < 19)  v = nw1[(k - 16) * 50 + m];
                else if (k == 19)            v = nb1[m];
            }
        } else if (i < 7424) {
            int j = i - W_NW2T; int m = j / 72, k = j % 72;
            if (m < 15) { if (k < 50) v = nw2[k * 15 + m]; else if (k == 50) v = nb2[m]; }
        }
        unsigned short h = f2bf(v);
        unsigned short l = f2bf(v - bf2f(h));
        wh[i] = h; wl[i] = l;
    }
}

// ---------- pad x to bf16 ushort4 ----------
__global__ __launch_bounds__(256) void xpad_kernel(
    const float* __restrict__ x, ushort4* __restrict__ x4b)
{
    int n = blockIdx.x * 256 + threadIdx.x;
    if (n >= N_NODES) return;
    ushort4 v;
    v.x = f2bf(x[n * 3 + 0]); v.y = f2bf(x[n * 3 + 1]);
    v.z = f2bf(x[n * 3 + 2]); v.w = 0;
    x4b[n] = v;
}

// ---------- in-degree histogram ----------
__global__ __launch_bounds__(256) void hist_kernel(
    const int* __restrict__ edge_index, int* __restrict__ counts)
{
    int e = blockIdx.x * 256 + threadIdx.x;
    if (e >= N_EDGES) return;
    atomicAdd(&counts[edge_index[e]], 1);
}

// ---------- CSR offsets ----------
__global__ __launch_bounds__(1024) void scan1_kernel(
    const int* __restrict__ counts, int* __restrict__ scanned, int* __restrict__ bsums)
{
    __shared__ int tmp[1024];
    int i = blockIdx.x * 1024 + threadIdx.x;
    int v = (i < N_NODES) ? counts[i] : 0;
    tmp[threadIdx.x] = v;
    __syncthreads();
    #pragma unroll
    for (int off = 1; off < 1024; off <<= 1) {
        int t = (threadIdx.x >= off) ? tmp[threadIdx.x - off] : 0;
        __syncthreads();
        tmp[threadIdx.x] += t;
        __syncthreads();
    }
    int incl = tmp[threadIdx.x];
    if (i < N_NODES) scanned[i] = incl - v;
    if (threadIdx.x == 1023) bsums[blockIdx.x] = incl;
}

__global__ __launch_bounds__(128) void scan2_kernel(
    const int* __restrict__ bsums, int* __restrict__ bofs)
{
    __shared__ int tmp[128];
    int v = (threadIdx.x < NBLK1) ? bsums[threadIdx.x] : 0;
    tmp[threadIdx.x] = v;
    __syncthreads();
    #pragma unroll
    for (int off = 1; off < 128; off <<= 1) {
        int t = (threadIdx.x >= off) ? tmp[threadIdx.x - off] : 0;
        __syncthreads();
        tmp[threadIdx.x] += t;
        __syncthreads();
    }
    if (threadIdx.x < NBLK1) bofs[threadIdx.x] = tmp[threadIdx.x] - v;
}

__global__ __launch_bounds__(256) void scan3_kernel(
    const int* __restrict__ scanned, const int* __restrict__ bofs,
    int* __restrict__ cursor)
{
    int n = blockIdx.x * 256 + threadIdx.x;
    if (n >= N_NODES) return;
    cursor[n] = scanned[n] + bofs[n >> 10];
}

// ---------- CSR edge-id scatter ----------
__global__ __launch_bounds__(256) void scatter_kernel(
    const int* __restrict__ edge_index, int* __restrict__ cursor,
    int* __restrict__ eids)
{
    int e = blockIdx.x * 256 + threadIdx.x;
    if (e >= N_EDGES) return;
    int row = edge_index[e];
    int pos = atomicAdd(&cursor[row], 1);
    eids[pos] = e;
}

// ---------- MFMA edge MLP: 16 edges per wave, 4 chained GEMMs ----------
// A = weights (M=channels), B = edges (N=16 edges), split hi/lo weights.
__global__ __launch_bounds__(256) void edge_mfma_kernel(
    const unsigned short* __restrict__ wh_g, const unsigned short* __restrict__ wl_g,
    const ushort4* __restrict__ x4b, const float* __restrict__ edge_attr,
    const int* __restrict__ edge_index, const int* __restrict__ eids,
    float* __restrict__ msg)
{
    __shared__ unsigned short swh[W_TOTAL];
    __shared__ unsigned short swl[W_TOTAL];
    // per-wave activation buffers: ein[16][40] @0, h[16][72] @640, h2in[16][40] @1792
    __shared__ unsigned short act[4][2432];

    int tid = threadIdx.x;
    // stage weights (coalesced 16B copies)
    {
        const uint4* src_h = (const uint4*)wh_g;
        const uint4* src_l = (const uint4*)wl_g;
        uint4* dst_h = (uint4*)swh;
        uint4* dst_l = (uint4*)swl;
        for (int i = tid; i < W_TOTAL / 8; i += 256) { dst_h[i] = src_h[i]; dst_l[i] = src_l[i]; }
    }

    int wave = tid >> 6, lane = tid & 63;
    int t16 = lane & 15, quad = lane >> 4;
    unsigned short* ein  = &act[wave][0];
    unsigned short* hbuf = &act[wave][640];
    unsigned short* h2in = &act[wave][1792];

    int sid = blockIdx.x * 64 + wave * 16 + t16;   // CSR slot, grid covers exactly N_EDGES
    int eid = eids[sid];

    // stage per-edge inputs (by quad)
    if (quad == 0) {
        int row = edge_index[eid];
        ushort4 xr = x4b[row];
        ushort4 w; w.x = xr.x; w.y = xr.y; w.z = xr.z; w.w = 0x3F80;  // +bias ch3
        *(ushort4*)&ein[t16 * 40 + 0] = w;
        ushort4 z; z.x = 0; z.y = 0; z.z = 0; z.w = 0;
        *(ushort4*)&ein[t16 * 40 + 12] = z;
        *(ushort4*)&ein[t16 * 40 + 28] = z;
        *(ushort4*)&h2in[t16 * 40 + 20] = z;
        *(ushort4*)&h2in[t16 * 40 + 36] = z;
    } else if (quad == 1) {
        int col = edge_index[N_EDGES + eid];
        ushort4 xc = x4b[col];
        ushort4 w; w.x = xc.x; w.y = xc.y; w.z = xc.z; w.w = 0;
        *(ushort4*)&ein[t16 * 40 + 4] = w;
        ushort4 z; z.x = 0; z.y = 0; z.z = 0; z.w = 0;
        *(ushort4*)&ein[t16 * 40 + 16] = z;
        *(ushort4*)&ein[t16 * 40 + 32] = z;
        *(ushort4*)&h2in[t16 * 40 + 24] = z;
    } else if (quad == 2) {
        float a0 = edge_attr[eid * 3 + 0];
        float a1 = edge_attr[eid * 3 + 1];
        float a2 = edge_attr[eid * 3 + 2];
        ushort4 w; w.x = f2bf(a0); w.y = f2bf(a1); w.z = f2bf(a2); w.w = 0;
        *(ushort4*)&ein[t16 * 40 + 8] = w;
        ushort4 z; z.x = 0; z.y = 0; z.z = 0; z.w = 0;
        *(ushort4*)&ein[t16 * 40 + 20] = z;
        *(ushort4*)&ein[t16 * 40 + 36] = z;
        *(ushort4*)&h2in[t16 * 40 + 28] = z;
    } else {
        int col = edge_index[N_EDGES + eid];
        ushort4 xc = x4b[col];
        ushort4 w; w.x = xc.x; w.y = xc.y; w.z = xc.z; w.w = 0x3F80;  // +bias ch19
        *(ushort4*)&h2in[t16 * 40 + 16] = w;
        ushort4 z; z.x = 0; z.y = 0; z.z = 0; z.w = 0;
        *(ushort4*)&ein[t16 * 40 + 24] = z;
        *(ushort4*)&h2in[t16 * 40 + 32] = z;
    }
    __syncthreads();

    // ---- edge MLP layer 1: [64ch] x [K=32] ----
    short8 B1 = *(short8*)&ein[t16 * 40 + quad * 8];
    float4_ acc1[4];
    #pragma unroll
    for (int t4 = 0; t4 < 4; t4++) {
        int aoff = W_EW1T + (t4 * 16 + t16) * 40 + quad * 8;
        short8 Al = *(short8*)&swl[aoff];
        short8 Ah = *(short8*)&swh[aoff];
        float4_ z = {0.f, 0.f, 0.f, 0.f};
        z = __builtin_amdgcn_mfma_f32_16x16x32_bf16(Al, B1, z, 0, 0, 0);
        z = __builtin_amdgcn_mfma_f32_16x16x32_bf16(Ah, B1, z, 0, 0, 0);
        acc1[t4] = z;
    }
    #pragma unroll
    for (int t4 = 0; t4 < 4; t4++) {
        float r0 = fmaxf(acc1[t4][0], 0.f), r1 = fmaxf(acc1[t4][1], 0.f);
        float r2 = fmaxf(acc1[t4][2], 0.f), r3 = fmaxf(acc1[t4][3], 0.f);
        uint2 pk; pk.x = pkbf(r0, r1); pk.y = pkbf(r2, r3);
        *(uint2*)&hbuf[t16 * 72 + t4 * 16 + quad * 4] = pk;
    }
    if (quad == 0) hbuf[t16 * 72 + 50] = 0x3F80;   // bias channel
    __syncthreads();

    // ---- edge MLP layer 2: [16ch] x [K=64] ----
    float4_ acc2 = {0.f, 0.f, 0.f, 0.f};
    #pragma unroll
    for (int kc = 0; kc < 2; kc++) {
        int aoff = W_EW2T + t16 * 72 + kc * 32 + quad * 8;
        short8 B = *(short8*)&hbuf[t16 * 72 + kc * 32 + quad * 8];
        short8 Al = *(short8*)&swl[aoff];
        short8 Ah = *(short8*)&swh[aoff];
        acc2 = __builtin_amdgcn_mfma_f32_16x16x32_bf16(Al, B, acc2, 0, 0, 0);
        acc2 = __builtin_amdgcn_mfma_f32_16x16x32_bf16(Ah, B, acc2, 0, 0, 0);
    }
    {   // e2 (no relu) -> node-MLP input channels 0..15
        uint2 pk; pk.x = pkbf(acc2[0], acc2[1]); pk.y = pkbf(acc2[2], acc2[3]);
        *(uint2*)&h2in[t16 * 40 + quad * 4] = pk;
    }
    __syncthreads();

    // ---- node MLP layer 1: [64ch] x [K=32] ----
    short8 B3 = *(short8*)&h2in[t16 * 40 + quad * 8];
    float4_ acc3[4];
    #pragma unroll
    for (int t4 = 0; t4 < 4; t4++) {
        int aoff = W_NW1T + (t4 * 16 + t16) * 40 + quad * 8;
        short8 Al = *(short8*)&swl[aoff];
        short8 Ah = *(short8*)&swh[aoff];
        float4_ z = {0.f, 0.f, 0.f, 0.f};
        z = __builtin_amdgcn_mfma_f32_16x16x32_bf16(Al, B3, z, 0, 0, 0);
        z = __builtin_amdgcn_mfma_f32_16x16x32_bf16(Ah, B3, z, 0, 0, 0);
        acc3[t4] = z;
    }
    __syncthreads();   // hbuf readers (layer 2) are done; safe to overwrite
    #pragma unroll
    for (int t4 = 0; t4 < 4; t4++) {
        float r0 = fmaxf(acc3[t4][0], 0.f), r1 = fmaxf(acc3[t4][1], 0.f);
        float r2 = fmaxf(acc3[t4][2], 0.f), r3 = fmaxf(acc3[t4][3], 0.f);
        uint2 pk; pk.x = pkbf(r0, r1); pk.y = pkbf(r2, r3);
        *(uint2*)&hbuf[t16 * 72 + t4 * 16 + quad * 4] = pk;
    }
    if (quad == 0) hbuf[t16 * 72 + 50] = 0x3F80;
    __syncthreads();

    // ---- node MLP layer 2: [16ch] x [K=64] ----
    float4_ accm = {0.f, 0.f, 0.f, 0.f};
    #pragma unroll
    for (int kc = 0; kc < 2; kc++) {
        int aoff = W_NW2T + t16 * 72 + kc * 32 + quad * 8;
        short8 B = *(short8*)&hbuf[t16 * 72 + kc * 32 + quad * 8];
        short8 Al = *(short8*)&swl[aoff];
        short8 Ah = *(short8*)&swh[aoff];
        accm = __builtin_amdgcn_mfma_f32_16x16x32_bf16(Al, B, accm, 0, 0, 0);
        accm = __builtin_amdgcn_mfma_f32_16x16x32_bf16(Ah, B, accm, 0, 0, 0);
    }
    // store msg in CSR slot: rows quad*4+r = channels, col = edge (this lane's sid)
    *(float4_*)(msg + (size_t)sid * 16 + quad * 4) = accm;
}

// ---------- gather: sequential CSR segment sum ----------
__global__ __launch_bounds__(256) void gather_kernel(
    const float* __restrict__ msg, const int* __restrict__ scanned,
    const int* __restrict__ bofs, const int* __restrict__ counts,
    float* __restrict__ x2)
{
    int n = blockIdx.x * 256 + threadIdx.x;
    if (n >= N_NODES) return;
    int start = scanned[n] + bofs[n >> 10];
    int deg = counts[n];
    float4 a0 = make_float4(0.f, 0.f, 0.f, 0.f);
    float4 a1 = a0, a2 = a0, a3 = a0;
    for (int j = 0; j < deg; j++) {
        const float4* mp = (const float4*)(msg + (size_t)(start + j) * 16);
        float4 b0 = mp[0], b1 = mp[1], b2 = mp[2], b3 = mp[3];
        a0.x += b0.x; a0.y += b0.y; a0.z += b0.z; a0.w += b0.w;
        a1.x += b1.x; a1.y += b1.y; a1.z += b1.z; a1.w += b1.w;
        a2.x += b2.x; a2.y += b2.y; a2.z += b2.z; a2.w += b2.w;
        a3.x += b3.x; a3.y += b3.y; a3.z += b3.z;
    }
    float inv = 1.0f / fmaxf((float)deg, 1.0f);
    float4* xp = (float4*)(x2 + (size_t)n * 16);
    xp[0] = make_float4(a0.x * inv, a0.y * inv, a0.z * inv, a0.w * inv);
    xp[1] = make_float4(a1.x * inv, a1.y * inv, a1.z * inv, a1.w * inv);
    xp[2] = make_float4(a2.x * inv, a2.y * inv, a2.z * inv, a2.w * inv);
    xp[3] = make_float4(a3.x * inv, a3.y * inv, a3.z * inv, 0.0f);
}

// ---------- pool ----------
__global__ __launch_bounds__(256) void pool_kernel(
    const float* __restrict__ x2, const int* __restrict__ batch,
    float* __restrict__ gsum)
{
    __shared__ float acc[64 * 16];
    int n0 = blockIdx.x * 256;
    int n = n0 + threadIdx.x;
    int gmin = batch[n0];
    int gmax = batch[min(n0 + 255, N_NODES - 1)];
    int range = gmax - gmin + 1;
    if (range <= 64) {
        for (int t = threadIdx.x; t < range * 16; t += 256) acc[t] = 0.0f;
        __syncthreads();
        if (n < N_NODES) {
            int g = batch[n] - gmin;
            const float4* xp = (const float4*)(x2 + (size_t)n * 16);
            float4 a = xp[0], b = xp[1], c = xp[2], d = xp[3];
            float* dst = &acc[g * 16];
            atomicAdd(&dst[0], a.x);  atomicAdd(&dst[1], a.y);
            atomicAdd(&dst[2], a.z);  atomicAdd(&dst[3], a.w);
            atomicAdd(&dst[4], b.x);  atomicAdd(&dst[5], b.y);
            atomicAdd(&dst[6], b.z);  atomicAdd(&dst[7], b.w);
            atomicAdd(&dst[8], c.x);  atomicAdd(&dst[9], c.y);
            atomicAdd(&dst[10], c.z); atomicAdd(&dst[11], c.w);
            atomicAdd(&dst[12], d.x); atomicAdd(&dst[13], d.y);
            atomicAdd(&dst[14], d.z); atomicAdd(&dst[15], 1.0f);
        }
        __syncthreads();
        for (int t = threadIdx.x; t < range * 16; t += 256) {
            float v = acc[t];
            if (v != 0.0f) atomicAdd(&gsum[(size_t)gmin * 16 + t], v);
        }
    } else {
        if (n < N_NODES) {
            int g = batch[n];
            const float4* xp = (const float4*)(x2 + (size_t)n * 16);
            float4 a = xp[0], b = xp[1], c = xp[2], d = xp[3];
            float* dst = gsum + (size_t)g * 16;
            atomicAdd(&dst[0], a.x);  atomicAdd(&dst[1], a.y);
            atomicAdd(&dst[2], a.z);  atomicAdd(&dst[3], a.w);
            atomicAdd(&dst[4], b.x);  atomicAdd(&dst[5], b.y);
            atomicAdd(&dst[6], b.z);  atomicAdd(&dst[7], b.w);
            atomicAdd(&dst[8], c.x);  atomicAdd(&dst[9], c.y);
            atomicAdd(&dst[10], c.z); atomicAdd(&dst[11], c.w);
            atomicAdd(&dst[12], d.x); atomicAdd(&dst[13], d.y);
            atomicAdd(&dst[14], d.z); atomicAdd(&dst[15], 1.0f);
        }
    }
}

// ---------- head ----------
__global__ __launch_bounds__(512) void head_kernel(
    const float* __restrict__ gsum,
    const float* __restrict__ fc1w, const float* __restrict__ fc1b,
    const float* __restrict__ gamma, const float* __restrict__ beta,
    const float* __restrict__ fc2w, const float* __restrict__ fc2b,
    float* __restrict__ out)
{
    __shared__ float ssum[D5], ssq[D5], smu[D5], sistd[D5];
    int g = threadIdx.x;
    if (g < D5) { ssum[g] = 0.0f; ssq[g] = 0.0f; }
    __syncthreads();

    const float* src = gsum + (size_t)g * 16;
    float inv = 1.0f / fmaxf(src[15], 1.0f);
    float u[D3];
    #pragma unroll
    for (int k = 0; k < D3; k++) u[k] = src[k] * inv;

    float h[D5];
    #pragma unroll
    for (int c = 0; c < D5; c++) h[c] = fc1b[c];
    #pragma unroll
    for (int k = 0; k < D3; k++) {
        float v = u[k];
        #pragma unroll
        for (int c = 0; c < D5; c++) h[c] = fmaf(v, fc1w[k * D5 + c], h[c]);
    }

    int lane = threadIdx.x & 63;
    #pragma unroll
    for (int c = 0; c < D5; c++) {
        float v = h[c];
        float v2 = v * v;
        #pragma unroll
        for (int off = 32; off >= 1; off >>= 1) {
            v  += __shfl_xor(v,  off);
            v2 += __shfl_xor(v2, off);
        }
        if (lane == 0) { atomicAdd(&ssum[c], v); atomicAdd(&ssq[c], v2); }
    }
    __syncthreads();
    if (g < D5) {
        float mu = ssum[g] * (1.0f / NUM_GRAPHS);
        float var = ssq[g] * (1.0f / NUM_GRAPHS) - mu * mu;
        smu[g] = mu;
        sistd[g] = rsqrtf(var + BN_EPS);
    }
    __syncthreads();

    float hn[D5];
    #pragma unroll
    for (int c = 0; c < D5; c++) {
        float v = gamma[c] * (h[c] - smu[c]) * sistd[c] + beta[c];
        hn[c] = fmaxf(v, 0.0f);
    }

    float lg[NCLS];
    #pragma unroll
    for (int j = 0; j < NCLS; j++) lg[j] = fc2b[j];
    #pragma unroll
    for (int c = 0; c < D5; c++) {
        float v = hn[c];
        #pragma unroll
        for (int j = 0; j < NCLS; j++) lg[j] = fmaf(v, fc2w[c * NCLS + j], lg[j]);
    }

    float m = lg[0];
    #pragma unroll
    for (int j = 1; j < NCLS; j++) m = fmaxf(m, lg[j]);
    float se = 0.0f;
    #pragma unroll
    for (int j = 0; j < NCLS; j++) se += expf(lg[j] - m);
    float lse = logf(se);
    #pragma unroll
    for (int j = 0; j < NCLS; j++) out[g * NCLS + j] = lg[j] - m - lse;
}

extern "C" void kernel_launch(void* const* d_in, const int* in_sizes, int n_in,
                              void* d_out, int out_size, void* d_ws, size_t ws_size,
                              hipStream_t stream) {
    const float* x         = (const float*)d_in[0];
    const float* edge_attr = (const float*)d_in[1];
    const float* ew1  = (const float*)d_in[2];
    const float* eb1  = (const float*)d_in[3];
    const float* ew2  = (const float*)d_in[4];
    const float* eb2  = (const float*)d_in[5];
    const float* nw1  = (const float*)d_in[6];
    const float* nb1  = (const float*)d_in[7];
    const float* nw2  = (const float*)d_in[8];
    const float* nb2  = (const float*)d_in[9];
    const float* fc1w = (const float*)d_in[10];
    const float* fc1b = (const float*)d_in[11];
    const float* gamma= (const float*)d_in[12];
    const float* beta = (const float*)d_in[13];
    const float* fc2w = (const float*)d_in[14];
    const float* fc2b = (const float*)d_in[15];
    const int* edge_index = (const int*)d_in[16];
    const int* batch      = (const int*)d_in[17];

    // workspace layout
    char* p = (char*)d_ws;
    float* msg = (float*)p;            p += (size_t)N_EDGES * 16 * sizeof(float);  // 102.4 MB
    int* eids    = (int*)p;            p += (size_t)N_EDGES * sizeof(int);         // 6.4 MB
    int* counts  = (int*)p;            p += (size_t)N_NODES * sizeof(int);
    int* scanned = (int*)p;            p += (size_t)N_NODES * sizeof(int);
    int* cursor  = (int*)p;            p += (size_t)N_NODES * sizeof(int);
    int* bsums   = (int*)p;            p += 128 * sizeof(int);
    int* bofs    = (int*)p;            p += 128 * sizeof(int);
    ushort4* x4b = (ushort4*)p;        p += (size_t)N_NODES * sizeof(ushort4);     // 0.8 MB
    float* x2    = (float*)p;          p += (size_t)N_NODES * 16 * sizeof(float);  // 6.4 MB
    float* gsum  = (float*)p;          p += (size_t)NUM_GRAPHS * 16 * sizeof(float);
    unsigned short* wh = (unsigned short*)p; p += W_TOTAL * sizeof(unsigned short);
    unsigned short* wl = (unsigned short*)p; p += W_TOTAL * sizeof(unsigned short);

    hipMemsetAsync(counts, 0, (size_t)N_NODES * sizeof(int), stream);
    hipMemsetAsync(gsum, 0, (size_t)NUM_GRAPHS * 16 * sizeof(float), stream);

    int egrid = (N_EDGES + 255) / 256;
    int ngrid = (N_NODES + 255) / 256;

    wprep_kernel<<<1, 256, 0, stream>>>(ew1, eb1, ew2, eb2, nw1, nb1, nw2, nb2, wh, wl);
    xpad_kernel<<<ngrid, 256, 0, stream>>>(x, x4b);
    hist_kernel<<<egrid, 256, 0, stream>>>(edge_index, counts);
    scan1_kernel<<<NBLK1, 1024, 0, stream>>>(counts, scanned, bsums);
    scan2_kernel<<<1, 128, 0, stream>>>(bsums, bofs);
    scan3_kernel<<<ngrid, 256, 0, stream>>>(scanned, bofs, cursor);
    scatter_kernel<<<egrid, 256, 0, stream>>>(edge_index, cursor, eids);
    edge_mfma_kernel<<<N_EDGES / 64, 256, 0, stream>>>(
        wh, wl, x4b, edge_attr, edge_index, eids, msg);
    gather_kernel<<<ngrid, 256, 0, stream>>>(msg, scanned, bofs, counts, x2);
    pool_kernel<<<ngrid, 256, 0, stream>>>(x2, batch, gsum);
    head_kernel<<<1, 512, 0, stream>>>(
        gsum, fc1w, fc1b, gamma, beta, fc2w, fc2b, (float*)d_out);
}

// Round 5
// 382.374 us; speedup vs baseline: 1.4739x; 1.4739x over previous
//
#include <hip/hip_runtime.h>
#include <hip/hip_bf16.h>
#include <math.h>

#define N_NODES    100000
#define N_EDGES    1600000
#define NUM_GRAPHS 512
#define D2 50
#define D3 15
#define D5 10
#define NCLS 6
#define BN_EPS 1e-5f

#define NBLK1 ((N_NODES + 1023) / 1024)   // 98 scan blocks

// global bf16 weight buffer layout (elements), padded/transposed
// ew1T [64 m][40 k] : k0-2 x_row, k3 bias, k4-6 x_col, k8-10 ea
// ew2T [16 m][72 k] : k0-49 h1, k50 bias
// nw1T [64 m][40 k] : k0-14 e2, k16-18 x_col, k19 bias
// nw2T [16 m][72 k] : k0-49 h2, k50 bias
#define W_EW1T 0
#define W_EW2T 2560
#define W_NW1T 3712
#define W_NW2T 6272
#define W_TOTAL 7680

// per-wave LDS activation layout (ushorts): ein[16][40] @0, hbuf[16][104] @640, h2in[16][40] @2304
#define S_EIN  40
#define S_HB   104
#define ACT_WAVE 2944

typedef __attribute__((ext_vector_type(8))) short short8;
typedef __attribute__((ext_vector_type(4))) float float4_;

__device__ __forceinline__ unsigned short f2bf(float f) {
    __hip_bfloat16 h = __float2bfloat16(f);
    union { __hip_bfloat16 h; unsigned short u; } c; c.h = h; return c.u;
}
__device__ __forceinline__ float bf2f(unsigned short u) {
    union { __hip_bfloat16 h; unsigned short u; } c; c.u = u;
    return __bfloat162float(c.h);
}
__device__ __forceinline__ unsigned int pkbf(float a, float b) {
    return (unsigned int)f2bf(a) | ((unsigned int)f2bf(b) << 16);
}

// ---------- fused prep: weight split/transpose + x pad + in-degree histogram ----------
__global__ __launch_bounds__(256) void prep_kernel(
    const float* __restrict__ ew1, const float* __restrict__ eb1,
    const float* __restrict__ ew2, const float* __restrict__ eb2,
    const float* __restrict__ nw1, const float* __restrict__ nb1,
    const float* __restrict__ nw2, const float* __restrict__ nb2,
    unsigned short* __restrict__ wh, unsigned short* __restrict__ wl,
    const float* __restrict__ x, ushort4* __restrict__ x4b,
    const int* __restrict__ edge_index, int* __restrict__ counts)
{
    int gtid = blockIdx.x * 256 + threadIdx.x;
    int gsz = gridDim.x * 256;

    for (int i = gtid; i < W_TOTAL; i += gsz) {
        float v = 0.0f;
        if (i < W_EW2T) {
            int m = i / 40, k = i % 40;
            if (m < 50) {
                if (k < 3)                 v = ew1[k * 50 + m];
                else if (k == 3)           v = eb1[m];
                else if (k >= 4 && k < 7)  v = ew1[(k - 1) * 50 + m];
                else if (k >= 8 && k < 11) v = ew1[(k - 2) * 50 + m];
            }
        } else if (i < W_NW1T) {
            int j = i - W_EW2T; int m = j / 72, k = j % 72;
            if (m < 15) { if (k < 50) v = ew2[k * 15 + m]; else if (k == 50) v = eb2[m]; }
        } else if (i < W_NW2T) {
            int j = i - W_NW1T; int m = j / 40, k = j % 40;
            if (m < 50) {
                if (k < 15)                  v = nw1[(3 + k) * 50 + m];
                else if (k >= 16 && k < 19)  v = nw1[(k - 16) * 50 + m];
                else if (k == 19)            v = nb1[m];
            }
        } else if (i < 7424) {
            int j = i - W_NW2T; int m = j / 72, k = j % 72;
            if (m < 15) { if (k < 50) v = nw2[k * 15 + m]; else if (k == 50) v = nb2[m]; }
        }
        unsigned short h = f2bf(v);
        unsigned short l = f2bf(v - bf2f(h));
        wh[i] = h; wl[i] = l;
    }

    for (int n = gtid; n < N_NODES; n += gsz) {
        ushort4 v;
        v.x = f2bf(x[n * 3 + 0]); v.y = f2bf(x[n * 3 + 1]);
        v.z = f2bf(x[n * 3 + 2]); v.w = 0;
        x4b[n] = v;
    }

    for (int e = gtid; e < N_EDGES; e += gsz)
        atomicAdd(&counts[edge_index[e]], 1);
}

// ---------- CSR offsets ----------
__global__ __launch_bounds__(1024) void scan1_kernel(
    const int* __restrict__ counts, int* __restrict__ scanned, int* __restrict__ bsums)
{
    __shared__ int tmp[1024];
    int i = blockIdx.x * 1024 + threadIdx.x;
    int v = (i < N_NODES) ? counts[i] : 0;
    tmp[threadIdx.x] = v;
    __syncthreads();
    #pragma unroll
    for (int off = 1; off < 1024; off <<= 1) {
        int t = (threadIdx.x >= off) ? tmp[threadIdx.x - off] : 0;
        __syncthreads();
        tmp[threadIdx.x] += t;
        __syncthreads();
    }
    int incl = tmp[threadIdx.x];
    if (i < N_NODES) scanned[i] = incl - v;
    if (threadIdx.x == 1023) bsums[blockIdx.x] = incl;
}

__global__ __launch_bounds__(128) void scan2_kernel(
    const int* __restrict__ bsums, int* __restrict__ bofs)
{
    __shared__ int tmp[128];
    int v = (threadIdx.x < NBLK1) ? bsums[threadIdx.x] : 0;
    tmp[threadIdx.x] = v;
    __syncthreads();
    #pragma unroll
    for (int off = 1; off < 128; off <<= 1) {
        int t = (threadIdx.x >= off) ? tmp[threadIdx.x - off] : 0;
        __syncthreads();
        tmp[threadIdx.x] += t;
        __syncthreads();
    }
    if (threadIdx.x < NBLK1) bofs[threadIdx.x] = tmp[threadIdx.x] - v;
}

__global__ __launch_bounds__(256) void scan3_kernel(
    const int* __restrict__ scanned, const int* __restrict__ bofs,
    int* __restrict__ cursor)
{
    int n = blockIdx.x * 256 + threadIdx.x;
    if (n >= N_NODES) return;
    cursor[n] = scanned[n] + bofs[n >> 10];
}

// ---------- MFMA edge MLP: weights in registers, 25 tiles of 16 edges per wave ----------
__global__ __launch_bounds__(256) void edge_mfma_kernel(
    const unsigned short* __restrict__ wh_g, const unsigned short* __restrict__ wl_g,
    const ushort4* __restrict__ x4b, const float* __restrict__ edge_attr,
    const int* __restrict__ edge_index,
    int* __restrict__ cursor, float* __restrict__ msg)
{
    __shared__ unsigned short act[4][ACT_WAVE];

    int tid = threadIdx.x, wave = tid >> 6, lane = tid & 63;
    int t16 = lane & 15, quad = lane >> 4;
    unsigned short* ein  = &act[wave][0];
    unsigned short* hbuf = &act[wave][640];
    unsigned short* h2in = &act[wave][2304];

    // A-fragments (weights) -> registers, once per wave
    short8 A1h[4], A1l[4], A3h[4], A3l[4];
    #pragma unroll
    for (int t4 = 0; t4 < 4; t4++) {
        int o1 = W_EW1T + (t4 * 16 + t16) * 40 + quad * 8;
        A1h[t4] = *(const short8*)(wh_g + o1);
        A1l[t4] = *(const short8*)(wl_g + o1);
        int o3 = W_NW1T + (t4 * 16 + t16) * 40 + quad * 8;
        A3h[t4] = *(const short8*)(wh_g + o3);
        A3l[t4] = *(const short8*)(wl_g + o3);
    }
    short8 A2h[2], A2l[2], A4h[2], A4l[2];
    #pragma unroll
    for (int kc = 0; kc < 2; kc++) {
        int o2 = W_EW2T + t16 * 72 + kc * 32 + quad * 8;
        A2h[kc] = *(const short8*)(wh_g + o2);
        A2l[kc] = *(const short8*)(wl_g + o2);
        int o4 = W_NW2T + t16 * 72 + kc * 32 + quad * 8;
        A4h[kc] = *(const short8*)(wh_g + o4);
        A4l[kc] = *(const short8*)(wl_g + o4);
    }

    // zero pad regions once (ein k12..31, h2in k20..31)
    ushort4 z4; z4.x = 0; z4.y = 0; z4.z = 0; z4.w = 0;
    for (int i = lane; i < 16 * 5; i += 64) {
        int r = i / 5, c = i % 5;
        *(ushort4*)&ein[r * S_EIN + 12 + c * 4] = z4;
    }
    for (int i = lane; i < 16 * 3; i += 64) {
        int r = i / 3, c = i % 3;
        *(ushort4*)&h2in[r * S_EIN + 20 + c * 4] = z4;
    }
    __builtin_amdgcn_wave_barrier();

    int gw = blockIdx.x * 4 + wave;         // 1000 blocks * 4 waves = 4000 waves
    for (int t = gw; t < N_EDGES / 16; t += 4000) {
        int e = t * 16 + t16;
        int pos = 0;
        // stage per-edge inputs (by quad); wave-private LDS, DS pipe is in-order
        if (quad == 0) {
            int row = edge_index[e];
            ushort4 xr = x4b[row];
            ushort4 w; w.x = xr.x; w.y = xr.y; w.z = xr.z; w.w = 0x3F80;  // bias ch3
            *(ushort4*)&ein[t16 * S_EIN + 0] = w;
            pos = atomicAdd(&cursor[row], 1);
        } else if (quad == 1) {
            int col = edge_index[N_EDGES + e];
            ushort4 xc = x4b[col];           // .w == 0
            *(ushort4*)&ein[t16 * S_EIN + 4] = xc;
        } else if (quad == 2) {
            ushort4 w;
            w.x = f2bf(edge_attr[e * 3 + 0]);
            w.y = f2bf(edge_attr[e * 3 + 1]);
            w.z = f2bf(edge_attr[e * 3 + 2]);
            w.w = 0;
            *(ushort4*)&ein[t16 * S_EIN + 8] = w;
        } else {
            int col = edge_index[N_EDGES + e];
            ushort4 xc = x4b[col];
            ushort4 w; w.x = xc.x; w.y = xc.y; w.z = xc.z; w.w = 0x3F80;  // bias ch19
            *(ushort4*)&h2in[t16 * S_EIN + 16] = w;
        }
        pos = __shfl(pos, t16);
        __builtin_amdgcn_wave_barrier();

        // ---- edge MLP layer 1: [64ch] x K=32 ----
        short8 B1 = *(short8*)&ein[t16 * S_EIN + quad * 8];
        #pragma unroll
        for (int t4 = 0; t4 < 4; t4++) {
            float4_ z = {0.f, 0.f, 0.f, 0.f};
            z = __builtin_amdgcn_mfma_f32_16x16x32_bf16(A1l[t4], B1, z, 0, 0, 0);
            z = __builtin_amdgcn_mfma_f32_16x16x32_bf16(A1h[t4], B1, z, 0, 0, 0);
            float r0 = fmaxf(z[0], 0.f), r1 = fmaxf(z[1], 0.f);
            float r2 = fmaxf(z[2], 0.f), r3 = fmaxf(z[3], 0.f);
            uint2 pk; pk.x = pkbf(r0, r1); pk.y = pkbf(r2, r3);
            *(uint2*)&hbuf[t16 * S_HB + t4 * 16 + quad * 4] = pk;
        }
        if (quad == 0) hbuf[t16 * S_HB + 50] = 0x3F80;   // bias channel
        __builtin_amdgcn_wave_barrier();

        // ---- edge MLP layer 2: [16ch] x K=64 ----
        float4_ acc2 = {0.f, 0.f, 0.f, 0.f};
        #pragma unroll
        for (int kc = 0; kc < 2; kc++) {
            short8 B = *(short8*)&hbuf[t16 * S_HB + kc * 32 + quad * 8];
            acc2 = __builtin_amdgcn_mfma_f32_16x16x32_bf16(A2l[kc], B, acc2, 0, 0, 0);
            acc2 = __builtin_amdgcn_mfma_f32_16x16x32_bf16(A2h[kc], B, acc2, 0, 0, 0);
        }
        {   // e2 (no relu) -> node-MLP input channels 0..15
            uint2 pk; pk.x = pkbf(acc2[0], acc2[1]); pk.y = pkbf(acc2[2], acc2[3]);
            *(uint2*)&h2in[t16 * S_EIN + quad * 4] = pk;
        }
        __builtin_amdgcn_wave_barrier();

        // ---- node MLP layer 1: [64ch] x K=32 ----
        short8 B3 = *(short8*)&h2in[t16 * S_EIN + quad * 8];
        #pragma unroll
        for (int t4 = 0; t4 < 4; t4++) {
            float4_ z = {0.f, 0.f, 0.f, 0.f};
            z = __builtin_amdgcn_mfma_f32_16x16x32_bf16(A3l[t4], B3, z, 0, 0, 0);
            z = __builtin_amdgcn_mfma_f32_16x16x32_bf16(A3h[t4], B3, z, 0, 0, 0);
            float r0 = fmaxf(z[0], 0.f), r1 = fmaxf(z[1], 0.f);
            float r2 = fmaxf(z[2], 0.f), r3 = fmaxf(z[3], 0.f);
            uint2 pk; pk.x = pkbf(r0, r1); pk.y = pkbf(r2, r3);
            *(uint2*)&hbuf[t16 * S_HB + t4 * 16 + quad * 4] = pk;
        }
        if (quad == 0) hbuf[t16 * S_HB + 50] = 0x3F80;
        __builtin_amdgcn_wave_barrier();

        // ---- node MLP layer 2: [16ch] x K=64 ----
        float4_ accm = {0.f, 0.f, 0.f, 0.f};
        #pragma unroll
        for (int kc = 0; kc < 2; kc++) {
            short8 B = *(short8*)&hbuf[t16 * S_HB + kc * 32 + quad * 8];
            accm = __builtin_amdgcn_mfma_f32_16x16x32_bf16(A4l[kc], B, accm, 0, 0, 0);
            accm = __builtin_amdgcn_mfma_f32_16x16x32_bf16(A4h[kc], B, accm, 0, 0, 0);
        }
        // store to this edge's CSR slot: channel = quad*4+reg, col = edge t16
        *(float4_*)(msg + (size_t)pos * 16 + quad * 4) = accm;
        __builtin_amdgcn_wave_barrier();
    }
}

// ---------- fused gather (CSR segment mean) + pool (sorted batch) ----------
__global__ __launch_bounds__(256) void gather_pool_kernel(
    const float* __restrict__ msg, const int* __restrict__ scanned,
    const int* __restrict__ bofs, const int* __restrict__ counts,
    const int* __restrict__ batch, float* __restrict__ gsum)
{
    __shared__ float acc[64 * 16];
    int n0 = blockIdx.x * 256;
    int n = n0 + threadIdx.x;

    float v[16];
    #pragma unroll
    for (int k = 0; k < 16; k++) v[k] = 0.0f;
    if (n < N_NODES) {
        int start = scanned[n] + bofs[n >> 10];
        int deg = counts[n];
        for (int j = 0; j < deg; j++) {
            const float4* mp = (const float4*)(msg + (size_t)(start + j) * 16);
            float4 b0 = mp[0], b1 = mp[1], b2 = mp[2], b3 = mp[3];
            v[0] += b0.x;  v[1] += b0.y;  v[2] += b0.z;  v[3] += b0.w;
            v[4] += b1.x;  v[5] += b1.y;  v[6] += b1.z;  v[7] += b1.w;
            v[8] += b2.x;  v[9] += b2.y;  v[10] += b2.z; v[11] += b2.w;
            v[12] += b3.x; v[13] += b3.y; v[14] += b3.z;
        }
        float inv = 1.0f / fmaxf((float)deg, 1.0f);
        #pragma unroll
        for (int k = 0; k < 15; k++) v[k] *= inv;
        v[15] = 1.0f;   // node count
    }

    int gmin = batch[n0];
    int gmax = batch[min(n0 + 255, N_NODES - 1)];
    int range = gmax - gmin + 1;
    if (range <= 64) {
        for (int t = threadIdx.x; t < range * 16; t += 256) acc[t] = 0.0f;
        __syncthreads();
        if (n < N_NODES) {
            int g = batch[n] - gmin;
            float* dst = &acc[g * 16];
            #pragma unroll
            for (int k = 0; k < 16; k++) atomicAdd(&dst[k], v[k]);
        }
        __syncthreads();
        for (int t = threadIdx.x; t < range * 16; t += 256) {
            float w = acc[t];
            if (w != 0.0f) atomicAdd(&gsum[(size_t)gmin * 16 + t], w);
        }
    } else {
        if (n < N_NODES) {
            int g = batch[n];
            float* dst = gsum + (size_t)g * 16;
            #pragma unroll
            for (int k = 0; k < 16; k++) atomicAdd(&dst[k], v[k]);
        }
    }
}

// ---------- head ----------
__global__ __launch_bounds__(512) void head_kernel(
    const float* __restrict__ gsum,
    const float* __restrict__ fc1w, const float* __restrict__ fc1b,
    const float* __restrict__ gamma, const float* __restrict__ beta,
    const float* __restrict__ fc2w, const float* __restrict__ fc2b,
    float* __restrict__ out)
{
    __shared__ float ssum[D5], ssq[D5], smu[D5], sistd[D5];
    int g = threadIdx.x;
    if (g < D5) { ssum[g] = 0.0f; ssq[g] = 0.0f; }
    __syncthreads();

    const float* src = gsum + (size_t)g * 16;
    float inv = 1.0f / fmaxf(src[15], 1.0f);
    float u[D3];
    #pragma unroll
    for (int k = 0; k < D3; k++) u[k] = src[k] * inv;

    float h[D5];
    #pragma unroll
    for (int c = 0; c < D5; c++) h[c] = fc1b[c];
    #pragma unroll
    for (int k = 0; k < D3; k++) {
        float v = u[k];
        #pragma unroll
        for (int c = 0; c < D5; c++) h[c] = fmaf(v, fc1w[k * D5 + c], h[c]);
    }

    int lane = threadIdx.x & 63;
    #pragma unroll
    for (int c = 0; c < D5; c++) {
        float v = h[c];
        float v2 = v * v;
        #pragma unroll
        for (int off = 32; off >= 1; off >>= 1) {
            v  += __shfl_xor(v,  off);
            v2 += __shfl_xor(v2, off);
        }
        if (lane == 0) { atomicAdd(&ssum[c], v); atomicAdd(&ssq[c], v2); }
    }
    __syncthreads();
    if (g < D5) {
        float mu = ssum[g] * (1.0f / NUM_GRAPHS);
        float var = ssq[g] * (1.0f / NUM_GRAPHS) - mu * mu;
        smu[g] = mu;
        sistd[g] = rsqrtf(var + BN_EPS);
    }
    __syncthreads();

    float hn[D5];
    #pragma unroll
    for (int c = 0; c < D5; c++) {
        float v = gamma[c] * (h[c] - smu[c]) * sistd[c] + beta[c];
        hn[c] = fmaxf(v, 0.0f);
    }

    float lg[NCLS];
    #pragma unroll
    for (int j = 0; j < NCLS; j++) lg[j] = fc2b[j];
    #pragma unroll
    for (int c = 0; c < D5; c++) {
        float v = hn[c];
        #pragma unroll
        for (int j = 0; j < NCLS; j++) lg[j] = fmaf(v, fc2w[c * NCLS + j], lg[j]);
    }

    float m = lg[0];
    #pragma unroll
    for (int j = 1; j < NCLS; j++) m = fmaxf(m, lg[j]);
    float se = 0.0f;
    #pragma unroll
    for (int j = 0; j < NCLS; j++) se += expf(lg[j] - m);
    float lse = logf(se);
    #pragma unroll
    for (int j = 0; j < NCLS; j++) out[g * NCLS + j] = lg[j] - m - lse;
}

extern "C" void kernel_launch(void* const* d_in, const int* in_sizes, int n_in,
                              void* d_out, int out_size, void* d_ws, size_t ws_size,
                              hipStream_t stream) {
    const float* x         = (const float*)d_in[0];
    const float* edge_attr = (const float*)d_in[1];
    const float* ew1  = (const float*)d_in[2];
    const float* eb1  = (const float*)d_in[3];
    const float* ew2  = (const float*)d_in[4];
    const float* eb2  = (const float*)d_in[5];
    const float* nw1  = (const float*)d_in[6];
    const float* nb1  = (const float*)d_in[7];
    const float* nw2  = (const float*)d_in[8];
    const float* nb2  = (const float*)d_in[9];
    const float* fc1w = (const float*)d_in[10];
    const float* fc1b = (const float*)d_in[11];
    const float* gamma= (const float*)d_in[12];
    const float* beta = (const float*)d_in[13];
    const float* fc2w = (const float*)d_in[14];
    const float* fc2b = (const float*)d_in[15];
    const int* edge_index = (const int*)d_in[16];
    const int* batch      = (const int*)d_in[17];

    // workspace layout
    char* p = (char*)d_ws;
    float* msg = (float*)p;            p += (size_t)N_EDGES * 16 * sizeof(float);  // 102.4 MB
    int* counts  = (int*)p;            p += (size_t)N_NODES * sizeof(int);
    int* scanned = (int*)p;            p += (size_t)N_NODES * sizeof(int);
    int* cursor  = (int*)p;            p += (size_t)N_NODES * sizeof(int);
    int* bsums   = (int*)p;            p += 128 * sizeof(int);
    int* bofs    = (int*)p;            p += 128 * sizeof(int);
    ushort4* x4b = (ushort4*)p;        p += (size_t)N_NODES * sizeof(ushort4);     // 0.8 MB
    float* gsum  = (float*)p;          p += (size_t)NUM_GRAPHS * 16 * sizeof(float);
    unsigned short* wh = (unsigned short*)p; p += W_TOTAL * sizeof(unsigned short);
    unsigned short* wl = (unsigned short*)p; p += W_TOTAL * sizeof(unsigned short);

    hipMemsetAsync(counts, 0, (size_t)N_NODES * sizeof(int), stream);
    hipMemsetAsync(gsum, 0, (size_t)NUM_GRAPHS * 16 * sizeof(float), stream);

    int egrid = (N_EDGES + 255) / 256;
    int ngrid = (N_NODES + 255) / 256;

    prep_kernel<<<egrid, 256, 0, stream>>>(
        ew1, eb1, ew2, eb2, nw1, nb1, nw2, nb2, wh, wl,
        x, x4b, edge_index, counts);
    scan1_kernel<<<NBLK1, 1024, 0, stream>>>(counts, scanned, bsums);
    scan2_kernel<<<1, 128, 0, stream>>>(bsums, bofs);
    scan3_kernel<<<ngrid, 256, 0, stream>>>(scanned, bofs, cursor);
    edge_mfma_kernel<<<1000, 256, 0, stream>>>(
        wh, wl, x4b, edge_attr, edge_index, cursor, msg);
    gather_pool_kernel<<<ngrid, 256, 0, stream>>>(
        msg, scanned, bofs, counts, batch, gsum);
    head_kernel<<<1, 512, 0, stream>>>(
        gsum, fc1w, fc1b, gamma, beta, fc2w, fc2b, (float*)d_out);
}

// Round 6
// 357.978 us; speedup vs baseline: 1.5744x; 1.0681x over previous
//
#include <hip/hip_runtime.h>
#include <hip/hip_bf16.h>
#include <math.h>

#define N_NODES    100000
#define N_EDGES    1600000
#define NUM_GRAPHS 512
#define D2 50
#define D3 15
#define D5 10
#define NCLS 6
#define BN_EPS 1e-5f

#define NBLK1 ((N_NODES + 1023) / 1024)   // 98 scan blocks

// global bf16 weight buffer layout (elements), padded/transposed
#define W_EW1T 0
#define W_EW2T 2560
#define W_NW1T 3712
#define W_NW2T 6272
#define W_TOTAL 7680

// per-wave LDS activation layout (ushorts):
// einA[16][40] @0, einB @640, h2A[16][40] @1280, h2B @1920,
// hbA[16][104] @2560, hbB @4224  -> 5888 ushorts / wave
#define S_EIN  40
#define S_HB   104
#define ACT_WAVE 5888

#define EDGE_BLOCKS 2500
#define EDGE_WAVES  (EDGE_BLOCKS * 4)        // 10000
#define TILES32     (N_EDGES / 32)           // 50000
#define EDGE_ITERS  (TILES32 / EDGE_WAVES)   // 5

typedef __attribute__((ext_vector_type(8))) short short8;
typedef __attribute__((ext_vector_type(4))) float float4_;

__device__ __forceinline__ unsigned short f2bf(float f) {
    __hip_bfloat16 h = __float2bfloat16(f);
    union { __hip_bfloat16 h; unsigned short u; } c; c.h = h; return c.u;
}
__device__ __forceinline__ float bf2f(unsigned short u) {
    union { __hip_bfloat16 h; unsigned short u; } c; c.u = u;
    return __bfloat162float(c.h);
}
__device__ __forceinline__ unsigned int pkbf(float a, float b) {
    return (unsigned int)f2bf(a) | ((unsigned int)f2bf(b) << 16);
}

// ---------- fused prep: weight split/transpose + x pad + in-degree histogram ----------
__global__ __launch_bounds__(256) void prep_kernel(
    const float* __restrict__ ew1, const float* __restrict__ eb1,
    const float* __restrict__ ew2, const float* __restrict__ eb2,
    const float* __restrict__ nw1, const float* __restrict__ nb1,
    const float* __restrict__ nw2, const float* __restrict__ nb2,
    unsigned short* __restrict__ wh, unsigned short* __restrict__ wl,
    const float* __restrict__ x, ushort4* __restrict__ x4b,
    const int* __restrict__ edge_index, int* __restrict__ counts)
{
    int gtid = blockIdx.x * 256 + threadIdx.x;
    int gsz = gridDim.x * 256;

    for (int i = gtid; i < W_TOTAL; i += gsz) {
        float v = 0.0f;
        if (i < W_EW2T) {
            int m = i / 40, k = i % 40;
            if (m < 50) {
                if (k < 3)                 v = ew1[k * 50 + m];
                else if (k == 3)           v = eb1[m];
                else if (k >= 4 && k < 7)  v = ew1[(k - 1) * 50 + m];
                else if (k >= 8 && k < 11) v = ew1[(k - 2) * 50 + m];
            }
        } else if (i < W_NW1T) {
            int j = i - W_EW2T; int m = j / 72, k = j % 72;
            if (m < 15) { if (k < 50) v = ew2[k * 15 + m]; else if (k == 50) v = eb2[m]; }
        } else if (i < W_NW2T) {
            int j = i - W_NW1T; int m = j / 40, k = j % 40;
            if (m < 50) {
                if (k < 15)                  v = nw1[(3 + k) * 50 + m];
                else if (k >= 16 && k < 19)  v = nw1[(k - 16) * 50 + m];
                else if (k == 19)            v = nb1[m];
            }
        } else if (i < 7424) {
            int j = i - W_NW2T; int m = j / 72, k = j % 72;
            if (m < 15) { if (k < 50) v = nw2[k * 15 + m]; else if (k == 50) v = nb2[m]; }
        }
        unsigned short h = f2bf(v);
        unsigned short l = f2bf(v - bf2f(h));
        wh[i] = h; wl[i] = l;
    }

    for (int n = gtid; n < N_NODES; n += gsz) {
        ushort4 v;
        v.x = f2bf(x[n * 3 + 0]); v.y = f2bf(x[n * 3 + 1]);
        v.z = f2bf(x[n * 3 + 2]); v.w = 0;
        x4b[n] = v;
    }

    for (int e = gtid; e < N_EDGES; e += gsz)
        atomicAdd(&counts[edge_index[e]], 1);
}

// ---------- CSR offsets ----------
__global__ __launch_bounds__(1024) void scan1_kernel(
    const int* __restrict__ counts, int* __restrict__ scanned, int* __restrict__ bsums)
{
    __shared__ int tmp[1024];
    int i = blockIdx.x * 1024 + threadIdx.x;
    int v = (i < N_NODES) ? counts[i] : 0;
    tmp[threadIdx.x] = v;
    __syncthreads();
    #pragma unroll
    for (int off = 1; off < 1024; off <<= 1) {
        int t = (threadIdx.x >= off) ? tmp[threadIdx.x - off] : 0;
        __syncthreads();
        tmp[threadIdx.x] += t;
        __syncthreads();
    }
    int incl = tmp[threadIdx.x];
    if (i < N_NODES) scanned[i] = incl - v;
    if (threadIdx.x == 1023) bsums[blockIdx.x] = incl;
}

__global__ __launch_bounds__(128) void scan2_kernel(
    const int* __restrict__ bsums, int* __restrict__ bofs)
{
    __shared__ int tmp[128];
    int v = (threadIdx.x < NBLK1) ? bsums[threadIdx.x] : 0;
    tmp[threadIdx.x] = v;
    __syncthreads();
    #pragma unroll
    for (int off = 1; off < 128; off <<= 1) {
        int t = (threadIdx.x >= off) ? tmp[threadIdx.x - off] : 0;
        __syncthreads();
        tmp[threadIdx.x] += t;
        __syncthreads();
    }
    if (threadIdx.x < NBLK1) bofs[threadIdx.x] = tmp[threadIdx.x] - v;
}

__global__ __launch_bounds__(256) void scan3_kernel(
    const int* __restrict__ scanned, const int* __restrict__ bofs,
    int* __restrict__ cursor)
{
    int n = blockIdx.x * 256 + threadIdx.x;
    if (n >= N_NODES) return;
    cursor[n] = scanned[n] + bofs[n >> 10];
}

// ---------- staging helpers ----------
__device__ __forceinline__ void load_stage(int e, int quad,
    const int* __restrict__ edge_index, const ushort4* __restrict__ x4b,
    const float* __restrict__ edge_attr, int* __restrict__ cursor,
    ushort4& w, int& pos)
{
    if (quad == 0) {
        int row = edge_index[e];
        ushort4 xr = x4b[row];
        w.x = xr.x; w.y = xr.y; w.z = xr.z; w.w = 0x3F80;   // bias ch3
        pos = atomicAdd(&cursor[row], 1);
    } else if (quad == 1) {
        int col = edge_index[N_EDGES + e];
        w = x4b[col];                                        // .w == 0
    } else if (quad == 2) {
        w.x = f2bf(edge_attr[e * 3 + 0]);
        w.y = f2bf(edge_attr[e * 3 + 1]);
        w.z = f2bf(edge_attr[e * 3 + 2]);
        w.w = 0;
    } else {
        int col = edge_index[N_EDGES + e];
        ushort4 xc = x4b[col];
        w.x = xc.x; w.y = xc.y; w.z = xc.z; w.w = 0x3F80;   // bias ch19
    }
}

__device__ __forceinline__ void write_stage(
    unsigned short* ein, unsigned short* h2in, int t16, int quad, ushort4 w)
{
    if (quad < 3) *(ushort4*)&ein[t16 * S_EIN + quad * 4] = w;
    else          *(ushort4*)&h2in[t16 * S_EIN + 16] = w;
}

// ---------- MFMA edge MLP: 32 edges/wave-tile, VMEM+atomic prefetch ----------
__global__ __launch_bounds__(256) void edge_mfma_kernel(
    const unsigned short* __restrict__ wh_g, const unsigned short* __restrict__ wl_g,
    const ushort4* __restrict__ x4b, const float* __restrict__ edge_attr,
    const int* __restrict__ edge_index,
    int* __restrict__ cursor, float* __restrict__ msg)
{
    __shared__ unsigned short act[4][ACT_WAVE];

    int tid = threadIdx.x, wave = tid >> 6, lane = tid & 63;
    int t16 = lane & 15, quad = lane >> 4;
    unsigned short* base = act[wave];
    unsigned short* einA = base;
    unsigned short* einB = base + 640;
    unsigned short* h2A  = base + 1280;
    unsigned short* h2B  = base + 1920;
    unsigned short* hbA  = base + 2560;
    unsigned short* hbB  = base + 4224;

    // A-fragments (weights) -> registers, once per wave
    short8 A1h[4], A1l[4], A3h[4], A3l[4];
    #pragma unroll
    for (int t4 = 0; t4 < 4; t4++) {
        int o1 = W_EW1T + (t4 * 16 + t16) * 40 + quad * 8;
        A1h[t4] = *(const short8*)(wh_g + o1);
        A1l[t4] = *(const short8*)(wl_g + o1);
        int o3 = W_NW1T + (t4 * 16 + t16) * 40 + quad * 8;
        A3h[t4] = *(const short8*)(wh_g + o3);
        A3l[t4] = *(const short8*)(wl_g + o3);
    }
    short8 A2h[2], A2l[2], A4h[2], A4l[2];
    #pragma unroll
    for (int kc = 0; kc < 2; kc++) {
        int o2 = W_EW2T + t16 * 72 + kc * 32 + quad * 8;
        A2h[kc] = *(const short8*)(wh_g + o2);
        A2l[kc] = *(const short8*)(wl_g + o2);
        int o4 = W_NW2T + t16 * 72 + kc * 32 + quad * 8;
        A4h[kc] = *(const short8*)(wh_g + o4);
        A4l[kc] = *(const short8*)(wl_g + o4);
    }

    // zero pad regions once: ein k12..31 (5 vec4/row), h2 k20..31 (3 vec4/row), A and B
    ushort4 z4; z4.x = 0; z4.y = 0; z4.z = 0; z4.w = 0;
    for (int i = lane; i < 16 * 5; i += 64) {
        int r = i / 5, c = i % 5;
        *(ushort4*)&einA[r * S_EIN + 12 + c * 4] = z4;
        *(ushort4*)&einB[r * S_EIN + 12 + c * 4] = z4;
    }
    for (int i = lane; i < 16 * 3; i += 64) {
        int r = i / 3, c = i % 3;
        *(ushort4*)&h2A[r * S_EIN + 20 + c * 4] = z4;
        *(ushort4*)&h2B[r * S_EIN + 20 + c * 4] = z4;
    }
    __builtin_amdgcn_wave_barrier();

    int gw = blockIdx.x * 4 + wave;
    int t = gw;
    ushort4 wA, wB; int posA = 0, posB = 0;
    load_stage(t * 32 + t16,      quad, edge_index, x4b, edge_attr, cursor, wA, posA);
    load_stage(t * 32 + 16 + t16, quad, edge_index, x4b, edge_attr, cursor, wB, posB);

    for (int it = 0; it < EDGE_ITERS; it++) {
        write_stage(einA, h2A, t16, quad, wA);
        write_stage(einB, h2B, t16, quad, wB);
        int p0 = __shfl(posA, t16);
        int p1 = __shfl(posB, t16);
        __builtin_amdgcn_wave_barrier();

        // prefetch next tile (VMEM + atomic) into registers
        int tn = t + EDGE_WAVES;
        ushort4 nA = z4, nB = z4; int nposA = 0, nposB = 0;
        if (it + 1 < EDGE_ITERS) {
            load_stage(tn * 32 + t16,      quad, edge_index, x4b, edge_attr, cursor, nA, nposA);
            load_stage(tn * 32 + 16 + t16, quad, edge_index, x4b, edge_attr, cursor, nB, nposB);
        }

        // ---- layer 1: [64ch] x K=32, sub-tiles A/B interleaved ----
        short8 B1a = *(short8*)&einA[t16 * S_EIN + quad * 8];
        short8 B1b = *(short8*)&einB[t16 * S_EIN + quad * 8];
        #pragma unroll
        for (int t4 = 0; t4 < 4; t4++) {
            float4_ zA = {0.f, 0.f, 0.f, 0.f}, zB = {0.f, 0.f, 0.f, 0.f};
            zA = __builtin_amdgcn_mfma_f32_16x16x32_bf16(A1l[t4], B1a, zA, 0, 0, 0);
            zB = __builtin_amdgcn_mfma_f32_16x16x32_bf16(A1l[t4], B1b, zB, 0, 0, 0);
            zA = __builtin_amdgcn_mfma_f32_16x16x32_bf16(A1h[t4], B1a, zA, 0, 0, 0);
            zB = __builtin_amdgcn_mfma_f32_16x16x32_bf16(A1h[t4], B1b, zB, 0, 0, 0);
            uint2 pA, pB;
            pA.x = pkbf(fmaxf(zA[0], 0.f), fmaxf(zA[1], 0.f));
            pA.y = pkbf(fmaxf(zA[2], 0.f), fmaxf(zA[3], 0.f));
            pB.x = pkbf(fmaxf(zB[0], 0.f), fmaxf(zB[1], 0.f));
            pB.y = pkbf(fmaxf(zB[2], 0.f), fmaxf(zB[3], 0.f));
            *(uint2*)&hbA[t16 * S_HB + t4 * 16 + quad * 4] = pA;
            *(uint2*)&hbB[t16 * S_HB + t4 * 16 + quad * 4] = pB;
        }
        if (quad == 0) {
            hbA[t16 * S_HB + 50] = 0x3F80;
            hbB[t16 * S_HB + 50] = 0x3F80;
        }
        __builtin_amdgcn_wave_barrier();

        // ---- layer 2: [16ch] x K=64 ----
        float4_ a2A = {0.f, 0.f, 0.f, 0.f}, a2B = {0.f, 0.f, 0.f, 0.f};
        #pragma unroll
        for (int kc = 0; kc < 2; kc++) {
            short8 BA = *(short8*)&hbA[t16 * S_HB + kc * 32 + quad * 8];
            short8 BB = *(short8*)&hbB[t16 * S_HB + kc * 32 + quad * 8];
            a2A = __builtin_amdgcn_mfma_f32_16x16x32_bf16(A2l[kc], BA, a2A, 0, 0, 0);
            a2B = __builtin_amdgcn_mfma_f32_16x16x32_bf16(A2l[kc], BB, a2B, 0, 0, 0);
            a2A = __builtin_amdgcn_mfma_f32_16x16x32_bf16(A2h[kc], BA, a2A, 0, 0, 0);
            a2B = __builtin_amdgcn_mfma_f32_16x16x32_bf16(A2h[kc], BB, a2B, 0, 0, 0);
        }
        {
            uint2 pA, pB;
            pA.x = pkbf(a2A[0], a2A[1]); pA.y = pkbf(a2A[2], a2A[3]);
            pB.x = pkbf(a2B[0], a2B[1]); pB.y = pkbf(a2B[2], a2B[3]);
            *(uint2*)&h2A[t16 * S_EIN + quad * 4] = pA;
            *(uint2*)&h2B[t16 * S_EIN + quad * 4] = pB;
        }
        __builtin_amdgcn_wave_barrier();

        // ---- layer 3: [64ch] x K=32 ----
        short8 B3a = *(short8*)&h2A[t16 * S_EIN + quad * 8];
        short8 B3b = *(short8*)&h2B[t16 * S_EIN + quad * 8];
        #pragma unroll
        for (int t4 = 0; t4 < 4; t4++) {
            float4_ zA = {0.f, 0.f, 0.f, 0.f}, zB = {0.f, 0.f, 0.f, 0.f};
            zA = __builtin_amdgcn_mfma_f32_16x16x32_bf16(A3l[t4], B3a, zA, 0, 0, 0);
            zB = __builtin_amdgcn_mfma_f32_16x16x32_bf16(A3l[t4], B3b, zB, 0, 0, 0);
            zA = __builtin_amdgcn_mfma_f32_16x16x32_bf16(A3h[t4], B3a, zA, 0, 0, 0);
            zB = __builtin_amdgcn_mfma_f32_16x16x32_bf16(A3h[t4], B3b, zB, 0, 0, 0);
            uint2 pA, pB;
            pA.x = pkbf(fmaxf(zA[0], 0.f), fmaxf(zA[1], 0.f));
            pA.y = pkbf(fmaxf(zA[2], 0.f), fmaxf(zA[3], 0.f));
            pB.x = pkbf(fmaxf(zB[0], 0.f), fmaxf(zB[1], 0.f));
            pB.y = pkbf(fmaxf(zB[2], 0.f), fmaxf(zB[3], 0.f));
            *(uint2*)&hbA[t16 * S_HB + t4 * 16 + quad * 4] = pA;
            *(uint2*)&hbB[t16 * S_HB + t4 * 16 + quad * 4] = pB;
        }
        if (quad == 0) {
            hbA[t16 * S_HB + 50] = 0x3F80;
            hbB[t16 * S_HB + 50] = 0x3F80;
        }
        __builtin_amdgcn_wave_barrier();

        // ---- layer 4: [16ch] x K=64 ----
        float4_ mA = {0.f, 0.f, 0.f, 0.f}, mB = {0.f, 0.f, 0.f, 0.f};
        #pragma unroll
        for (int kc = 0; kc < 2; kc++) {
            short8 BA = *(short8*)&hbA[t16 * S_HB + kc * 32 + quad * 8];
            short8 BB = *(short8*)&hbB[t16 * S_HB + kc * 32 + quad * 8];
            mA = __builtin_amdgcn_mfma_f32_16x16x32_bf16(A4l[kc], BA, mA, 0, 0, 0);
            mB = __builtin_amdgcn_mfma_f32_16x16x32_bf16(A4l[kc], BB, mB, 0, 0, 0);
            mA = __builtin_amdgcn_mfma_f32_16x16x32_bf16(A4h[kc], BA, mA, 0, 0, 0);
            mB = __builtin_amdgcn_mfma_f32_16x16x32_bf16(A4h[kc], BB, mB, 0, 0, 0);
        }
        *(float4_*)(msg + (size_t)p0 * 16 + quad * 4) = mA;
        *(float4_*)(msg + (size_t)p1 * 16 + quad * 4) = mB;
        __builtin_amdgcn_wave_barrier();

        wA = nA; wB = nB; posA = nposA; posB = nposB; t = tn;
    }
}

// ---------- fused gather (CSR segment mean) + pool (sorted batch) ----------
__global__ __launch_bounds__(256) void gather_pool_kernel(
    const float* __restrict__ msg, const int* __restrict__ scanned,
    const int* __restrict__ bofs, const int* __restrict__ counts,
    const int* __restrict__ batch, float* __restrict__ gsum)
{
    __shared__ float acc[64 * 16];
    int n0 = blockIdx.x * 256;
    int n = n0 + threadIdx.x;

    float v[16];
    #pragma unroll
    for (int k = 0; k < 16; k++) v[k] = 0.0f;
    if (n < N_NODES) {
        int start = scanned[n] + bofs[n >> 10];
        int deg = counts[n];
        for (int j = 0; j < deg; j++) {
            const float4* mp = (const float4*)(msg + (size_t)(start + j) * 16);
            float4 b0 = mp[0], b1 = mp[1], b2 = mp[2], b3 = mp[3];
            v[0] += b0.x;  v[1] += b0.y;  v[2] += b0.z;  v[3] += b0.w;
            v[4] += b1.x;  v[5] += b1.y;  v[6] += b1.z;  v[7] += b1.w;
            v[8] += b2.x;  v[9] += b2.y;  v[10] += b2.z; v[11] += b2.w;
            v[12] += b3.x; v[13] += b3.y; v[14] += b3.z;
        }
        float inv = 1.0f / fmaxf((float)deg, 1.0f);
        #pragma unroll
        for (int k = 0; k < 15; k++) v[k] *= inv;
        v[15] = 1.0f;   // node count
    }

    int gmin = batch[n0];
    int gmax = batch[min(n0 + 255, N_NODES - 1)];
    int range = gmax - gmin + 1;
    if (range <= 64) {
        for (int t = threadIdx.x; t < range * 16; t += 256) acc[t] = 0.0f;
        __syncthreads();
        if (n < N_NODES) {
            int g = batch[n] - gmin;
            float* dst = &acc[g * 16];
            #pragma unroll
            for (int k = 0; k < 16; k++) atomicAdd(&dst[k], v[k]);
        }
        __syncthreads();
        for (int t = threadIdx.x; t < range * 16; t += 256) {
            float w = acc[t];
            if (w != 0.0f) atomicAdd(&gsum[(size_t)gmin * 16 + t], w);
        }
    } else {
        if (n < N_NODES) {
            int g = batch[n];
            float* dst = gsum + (size_t)g * 16;
            #pragma unroll
            for (int k = 0; k < 16; k++) atomicAdd(&dst[k], v[k]);
        }
    }
}

// ---------- head ----------
__global__ __launch_bounds__(512) void head_kernel(
    const float* __restrict__ gsum,
    const float* __restrict__ fc1w, const float* __restrict__ fc1b,
    const float* __restrict__ gamma, const float* __restrict__ beta,
    const float* __restrict__ fc2w, const float* __restrict__ fc2b,
    float* __restrict__ out)
{
    __shared__ float ssum[D5], ssq[D5], smu[D5], sistd[D5];
    int g = threadIdx.x;
    if (g < D5) { ssum[g] = 0.0f; ssq[g] = 0.0f; }
    __syncthreads();

    const float* src = gsum + (size_t)g * 16;
    float inv = 1.0f / fmaxf(src[15], 1.0f);
    float u[D3];
    #pragma unroll
    for (int k = 0; k < D3; k++) u[k] = src[k] * inv;

    float h[D5];
    #pragma unroll
    for (int c = 0; c < D5; c++) h[c] = fc1b[c];
    #pragma unroll
    for (int k = 0; k < D3; k++) {
        float v = u[k];
        #pragma unroll
        for (int c = 0; c < D5; c++) h[c] = fmaf(v, fc1w[k * D5 + c], h[c]);
    }

    int lane = threadIdx.x & 63;
    #pragma unroll
    for (int c = 0; c < D5; c++) {
        float v = h[c];
        float v2 = v * v;
        #pragma unroll
        for (int off = 32; off >= 1; off >>= 1) {
            v  += __shfl_xor(v,  off);
            v2 += __shfl_xor(v2, off);
        }
        if (lane == 0) { atomicAdd(&ssum[c], v); atomicAdd(&ssq[c], v2); }
    }
    __syncthreads();
    if (g < D5) {
        float mu = ssum[g] * (1.0f / NUM_GRAPHS);
        float var = ssq[g] * (1.0f / NUM_GRAPHS) - mu * mu;
        smu[g] = mu;
        sistd[g] = rsqrtf(var + BN_EPS);
    }
    __syncthreads();

    float hn[D5];
    #pragma unroll
    for (int c = 0; c < D5; c++) {
        float v = gamma[c] * (h[c] - smu[c]) * sistd[c] + beta[c];
        hn[c] = fmaxf(v, 0.0f);
    }

    float lg[NCLS];
    #pragma unroll
    for (int j = 0; j < NCLS; j++) lg[j] = fc2b[j];
    #pragma unroll
    for (int c = 0; c < D5; c++) {
        float v = hn[c];
        #pragma unroll
        for (int j = 0; j < NCLS; j++) lg[j] = fmaf(v, fc2w[c * NCLS + j], lg[j]);
    }

    float m = lg[0];
    #pragma unroll
    for (int j = 1; j < NCLS; j++) m = fmaxf(m, lg[j]);
    float se = 0.0f;
    #pragma unroll
    for (int j = 0; j < NCLS; j++) se += expf(lg[j] - m);
    float lse = logf(se);
    #pragma unroll
    for (int j = 0; j < NCLS; j++) out[g * NCLS + j] = lg[j] - m - lse;
}

extern "C" void kernel_launch(void* const* d_in, const int* in_sizes, int n_in,
                              void* d_out, int out_size, void* d_ws, size_t ws_size,
                              hipStream_t stream) {
    const float* x         = (const float*)d_in[0];
    const float* edge_attr = (const float*)d_in[1];
    const float* ew1  = (const float*)d_in[2];
    const float* eb1  = (const float*)d_in[3];
    const float* ew2  = (const float*)d_in[4];
    const float* eb2  = (const float*)d_in[5];
    const float* nw1  = (const float*)d_in[6];
    const float* nb1  = (const float*)d_in[7];
    const float* nw2  = (const float*)d_in[8];
    const float* nb2  = (const float*)d_in[9];
    const float* fc1w = (const float*)d_in[10];
    const float* fc1b = (const float*)d_in[11];
    const float* gamma= (const float*)d_in[12];
    const float* beta = (const float*)d_in[13];
    const float* fc2w = (const float*)d_in[14];
    const float* fc2b = (const float*)d_in[15];
    const int* edge_index = (const int*)d_in[16];
    const int* batch      = (const int*)d_in[17];

    // workspace layout
    char* p = (char*)d_ws;
    float* msg = (float*)p;            p += (size_t)N_EDGES * 16 * sizeof(float);  // 102.4 MB
    int* counts  = (int*)p;            p += (size_t)N_NODES * sizeof(int);
    int* scanned = (int*)p;            p += (size_t)N_NODES * sizeof(int);
    int* cursor  = (int*)p;            p += (size_t)N_NODES * sizeof(int);
    int* bsums   = (int*)p;            p += 128 * sizeof(int);
    int* bofs    = (int*)p;            p += 128 * sizeof(int);
    ushort4* x4b = (ushort4*)p;        p += (size_t)N_NODES * sizeof(ushort4);     // 0.8 MB
    float* gsum  = (float*)p;          p += (size_t)NUM_GRAPHS * 16 * sizeof(float);
    unsigned short* wh = (unsigned short*)p; p += W_TOTAL * sizeof(unsigned short);
    unsigned short* wl = (unsigned short*)p; p += W_TOTAL * sizeof(unsigned short);

    hipMemsetAsync(counts, 0, (size_t)N_NODES * sizeof(int), stream);
    hipMemsetAsync(gsum, 0, (size_t)NUM_GRAPHS * 16 * sizeof(float), stream);

    int egrid = (N_EDGES + 255) / 256;
    int ngrid = (N_NODES + 255) / 256;

    prep_kernel<<<egrid, 256, 0, stream>>>(
        ew1, eb1, ew2, eb2, nw1, nb1, nw2, nb2, wh, wl,
        x, x4b, edge_index, counts);
    scan1_kernel<<<NBLK1, 1024, 0, stream>>>(counts, scanned, bsums);
    scan2_kernel<<<1, 128, 0, stream>>>(bsums, bofs);
    scan3_kernel<<<ngrid, 256, 0, stream>>>(scanned, bofs, cursor);
    edge_mfma_kernel<<<EDGE_BLOCKS, 256, 0, stream>>>(
        wh, wl, x4b, edge_attr, edge_index, cursor, msg);
    gather_pool_kernel<<<ngrid, 256, 0, stream>>>(
        msg, scanned, bofs, counts, batch, gsum);
    head_kernel<<<1, 512, 0, stream>>>(
        gsum, fc1w, fc1b, gamma, beta, fc2w, fc2b, (float*)d_out);
}

// Round 7
// 354.502 us; speedup vs baseline: 1.5898x; 1.0098x over previous
//
#include <hip/hip_runtime.h>
#include <hip/hip_bf16.h>
#include <math.h>

#define N_NODES    100000
#define N_EDGES    1600000
#define NUM_GRAPHS 512
#define D2 50
#define D3 15
#define D5 10
#define NCLS 6
#define BN_EPS 1e-5f

#define NBLK1 ((N_NODES + 1023) / 1024)   // 98 scan blocks

// global bf16 weight buffer layout (elements), padded/transposed
// ew1T [64 m][40 k] : k0-2 x_row, k3 bias, k4-6 x_col, k8-10 ea
// ew2T [16 m][72 k] : k0-49 h1, k50 bias
// nw1T [64 m][40 k] : k0-14 e2, k16-18 x_col, k19 bias
// nw2T [16 m][72 k] : k0-49 h2, k50 bias
#define W_EW1T 0
#define W_EW2T 2560
#define W_NW1T 3712
#define W_NW2T 6272
#define W_TOTAL 7680

#define EDGE_BLOCKS 2500
#define EDGE_WAVES  (EDGE_BLOCKS * 4)        // 10000
#define TILES32     (N_EDGES / 32)           // 50000
#define EDGE_ITERS  (TILES32 / EDGE_WAVES)   // 5

typedef __attribute__((ext_vector_type(8))) short short8;
typedef __attribute__((ext_vector_type(4))) float float4_;
union BU { unsigned u[4]; short8 s; };

__device__ __forceinline__ unsigned short f2bf(float f) {
    __hip_bfloat16 h = __float2bfloat16(f);
    union { __hip_bfloat16 h; unsigned short u; } c; c.h = h; return c.u;
}
__device__ __forceinline__ float bf2f(unsigned short u) {
    union { __hip_bfloat16 h; unsigned short u; } c; c.u = u;
    return __bfloat162float(c.h);
}
__device__ __forceinline__ unsigned int pkbf(float a, float b) {
    return (unsigned int)f2bf(a) | ((unsigned int)f2bf(b) << 16);
}
__device__ __forceinline__ unsigned bp(int s4, unsigned v) {
    return (unsigned)__builtin_amdgcn_ds_bpermute(s4, (int)v);
}

// ---------- fused prep: weight split/transpose + x pad + in-degree histogram ----------
__global__ __launch_bounds__(256) void prep_kernel(
    const float* __restrict__ ew1, const float* __restrict__ eb1,
    const float* __restrict__ ew2, const float* __restrict__ eb2,
    const float* __restrict__ nw1, const float* __restrict__ nb1,
    const float* __restrict__ nw2, const float* __restrict__ nb2,
    unsigned short* __restrict__ wh, unsigned short* __restrict__ wl,
    const float* __restrict__ x, ushort4* __restrict__ x4b,
    const int* __restrict__ edge_index, int* __restrict__ counts)
{
    int gtid = blockIdx.x * 256 + threadIdx.x;
    int gsz = gridDim.x * 256;

    for (int i = gtid; i < W_TOTAL; i += gsz) {
        float v = 0.0f;
        if (i < W_EW2T) {
            int m = i / 40, k = i % 40;
            if (m < 50) {
                if (k < 3)                 v = ew1[k * 50 + m];
                else if (k == 3)           v = eb1[m];
                else if (k >= 4 && k < 7)  v = ew1[(k - 1) * 50 + m];
                else if (k >= 8 && k < 11) v = ew1[(k - 2) * 50 + m];
            }
        } else if (i < W_NW1T) {
            int j = i - W_EW2T; int m = j / 72, k = j % 72;
            if (m < 15) { if (k < 50) v = ew2[k * 15 + m]; else if (k == 50) v = eb2[m]; }
        } else if (i < W_NW2T) {
            int j = i - W_NW1T; int m = j / 40, k = j % 40;
            if (m < 50) {
                if (k < 15)                  v = nw1[(3 + k) * 50 + m];
                else if (k >= 16 && k < 19)  v = nw1[(k - 16) * 50 + m];
                else if (k == 19)            v = nb1[m];
            }
        } else if (i < 7424) {
            int j = i - W_NW2T; int m = j / 72, k = j % 72;
            if (m < 15) { if (k < 50) v = nw2[k * 15 + m]; else if (k == 50) v = nb2[m]; }
        }
        unsigned short h = f2bf(v);
        unsigned short l = f2bf(v - bf2f(h));
        wh[i] = h; wl[i] = l;
    }

    for (int n = gtid; n < N_NODES; n += gsz) {
        ushort4 v;
        v.x = f2bf(x[n * 3 + 0]); v.y = f2bf(x[n * 3 + 1]);
        v.z = f2bf(x[n * 3 + 2]); v.w = 0;
        x4b[n] = v;
    }

    for (int e = gtid; e < N_EDGES; e += gsz)
        atomicAdd(&counts[edge_index[e]], 1);
}

// ---------- CSR offsets ----------
__global__ __launch_bounds__(1024) void scan1_kernel(
    const int* __restrict__ counts, int* __restrict__ scanned, int* __restrict__ bsums)
{
    __shared__ int tmp[1024];
    int i = blockIdx.x * 1024 + threadIdx.x;
    int v = (i < N_NODES) ? counts[i] : 0;
    tmp[threadIdx.x] = v;
    __syncthreads();
    #pragma unroll
    for (int off = 1; off < 1024; off <<= 1) {
        int t = (threadIdx.x >= off) ? tmp[threadIdx.x - off] : 0;
        __syncthreads();
        tmp[threadIdx.x] += t;
        __syncthreads();
    }
    int incl = tmp[threadIdx.x];
    if (i < N_NODES) scanned[i] = incl - v;
    if (threadIdx.x == 1023) bsums[blockIdx.x] = incl;
}

__global__ __launch_bounds__(128) void scan2_kernel(
    const int* __restrict__ bsums, int* __restrict__ bofs)
{
    __shared__ int tmp[128];
    int v = (threadIdx.x < NBLK1) ? bsums[threadIdx.x] : 0;
    tmp[threadIdx.x] = v;
    __syncthreads();
    #pragma unroll
    for (int off = 1; off < 128; off <<= 1) {
        int t = (threadIdx.x >= off) ? tmp[threadIdx.x - off] : 0;
        __syncthreads();
        tmp[threadIdx.x] += t;
        __syncthreads();
    }
    if (threadIdx.x < NBLK1) bofs[threadIdx.x] = tmp[threadIdx.x] - v;
}

__global__ __launch_bounds__(256) void scan3_kernel(
    const int* __restrict__ scanned, const int* __restrict__ bofs,
    int* __restrict__ cursor)
{
    int n = blockIdx.x * 256 + threadIdx.x;
    if (n >= N_NODES) return;
    cursor[n] = scanned[n] + bofs[n >> 10];
}

// ---------- per-edge input fetch: each (quad,n) lane owns edge n's slice ----------
struct EIn { unsigned w0, w1, w2, w3, h0, h1; int pos; };

__device__ __forceinline__ EIn load_in(int ebase, int n, int quad,
    const int* __restrict__ edge_index, const ushort4* __restrict__ x4b,
    const float* __restrict__ edge_attr, int* __restrict__ cursor)
{
    EIn r; r.w0 = r.w1 = r.w2 = r.w3 = 0; r.h0 = r.h1 = 0; r.pos = 0;
    int e = ebase + n;
    if (quad == 0) {
        int row = edge_index[e];
        int col = edge_index[N_EDGES + e];
        ushort4 xr = x4b[row];
        ushort4 xc = x4b[col];
        r.w0 = (unsigned)xr.x | ((unsigned)xr.y << 16);   // k0,k1 = x_row
        r.w1 = (unsigned)xr.z | (0x3F80u << 16);          // k2, k3=bias
        r.w2 = (unsigned)xc.x | ((unsigned)xc.y << 16);   // k4,k5 = x_col
        r.w3 = (unsigned)xc.z;                            // k6, k7=0
        r.pos = atomicAdd(&cursor[row], 1);
    } else if (quad == 1) {
        r.w0 = pkbf(edge_attr[e * 3 + 0], edge_attr[e * 3 + 1]);  // k8,k9
        r.w1 = (unsigned)f2bf(edge_attr[e * 3 + 2]);              // k10, k11=0
    } else if (quad == 2) {
        int col = edge_index[N_EDGES + e];
        ushort4 xc = x4b[col];
        r.h0 = (unsigned)xc.x | ((unsigned)xc.y << 16);   // nodeMLP k16,k17
        r.h1 = (unsigned)xc.z | (0x3F80u << 16);          // k18, k19=bias
    }
    return r;
}

// 64-ch C output (4 blocks, packed pairs U[4][2]) -> two K=32 B fragments
__device__ __forceinline__ void perm64(const unsigned U[4][2], int s0, int s1, bool hi,
                                       short8& Bc0, short8& Bc1)
{
    BU b0, b1;
    {
        unsigned a0 = bp(s0, U[0][0]), a1 = bp(s0, U[1][0]);
        unsigned a2 = bp(s0, U[0][1]), a3 = bp(s0, U[1][1]);
        unsigned a4 = bp(s1, U[0][0]), a5 = bp(s1, U[1][0]);
        unsigned a6 = bp(s1, U[0][1]), a7 = bp(s1, U[1][1]);
        b0.u[0] = hi ? a1 : a0;
        b0.u[1] = hi ? a3 : a2;
        b0.u[2] = hi ? a5 : a4;
        b0.u[3] = hi ? a7 : a6;
    }
    {
        unsigned a0 = bp(s0, U[2][0]), a1 = bp(s0, U[3][0]);
        unsigned a2 = bp(s0, U[2][1]), a3 = bp(s0, U[3][1]);
        unsigned a4 = bp(s1, U[2][0]), a5 = bp(s1, U[3][0]);
        unsigned a6 = bp(s1, U[2][1]), a7 = bp(s1, U[3][1]);
        b1.u[0] = hi ? a1 : a0;
        b1.u[1] = hi ? a3 : a2;
        b1.u[2] = hi ? a5 : a4;
        b1.u[3] = hi ? a7 : a6;
    }
    Bc0 = b0.s; Bc1 = b1.s;
}

// 16-ch C output (packed U2[2]) + static x_col/bias part -> K=32 B fragment
__device__ __forceinline__ short8 perm16(const unsigned U2[2], int s0, int s1,
                                         int quad, unsigned h0, unsigned h1)
{
    BU d;
    d.u[0] = bp(s0, U2[0]);
    d.u[1] = bp(s0, U2[1]);
    d.u[2] = bp(s1, U2[0]);
    d.u[3] = bp(s1, U2[1]);
    if (quad == 2) { d.u[0] = h0; d.u[1] = h1; d.u[2] = 0; d.u[3] = 0; }
    else if (quad == 3) { d.u[0] = 0; d.u[1] = 0; d.u[2] = 0; d.u[3] = 0; }
    return d.s;
}

// ---------- MFMA edge MLP: no LDS, all layer transitions via ds_bpermute ----------
__global__ __launch_bounds__(256) void edge_mfma_kernel(
    const unsigned short* __restrict__ wh_g, const unsigned short* __restrict__ wl_g,
    const ushort4* __restrict__ x4b, const float* __restrict__ edge_attr,
    const int* __restrict__ edge_index,
    int* __restrict__ cursor, float* __restrict__ msg)
{
    int tid = threadIdx.x, wave = tid >> 6, lane = tid & 63;
    int n = lane & 15, quad = lane >> 4;

    // A-fragments (weights) -> registers, once per wave
    short8 A1h[4], A1l[4], A3h[4], A3l[4];
    #pragma unroll
    for (int t4 = 0; t4 < 4; t4++) {
        int o1 = W_EW1T + (t4 * 16 + n) * 40 + quad * 8;
        A1h[t4] = *(const short8*)(wh_g + o1);
        A1l[t4] = *(const short8*)(wl_g + o1);
        int o3 = W_NW1T + (t4 * 16 + n) * 40 + quad * 8;
        A3h[t4] = *(const short8*)(wh_g + o3);
        A3l[t4] = *(const short8*)(wl_g + o3);
    }
    short8 A2h[2], A2l[2], A4h[2], A4l[2];
    #pragma unroll
    for (int kc = 0; kc < 2; kc++) {
        int o2 = W_EW2T + n * 72 + kc * 32 + quad * 8;
        A2h[kc] = *(const short8*)(wh_g + o2);
        A2l[kc] = *(const short8*)(wl_g + o2);
        int o4 = W_NW2T + n * 72 + kc * 32 + quad * 8;
        A4h[kc] = *(const short8*)(wh_g + o4);
        A4l[kc] = *(const short8*)(wl_g + o4);
    }

    int s0 = ((quad & 1) * 32 + n) * 4;   // byte index for bpermute (lane*4)
    int s1 = s0 + 64;
    bool hi = (quad & 2) != 0;

    int t = blockIdx.x * 4 + wave;
    EIn cur0 = load_in(t * 32,      n, quad, edge_index, x4b, edge_attr, cursor);
    EIn cur1 = load_in(t * 32 + 16, n, quad, edge_index, x4b, edge_attr, cursor);

    for (int it = 0; it < EDGE_ITERS; it++) {
        int p0 = __shfl(cur0.pos, n);
        int p1 = __shfl(cur1.pos, n);

        int tn = t + EDGE_WAVES;
        EIn nx0, nx1;
        nx0.w0 = nx0.w1 = nx0.w2 = nx0.w3 = nx0.h0 = nx0.h1 = 0; nx0.pos = 0;
        nx1 = nx0;
        if (it + 1 < EDGE_ITERS) {
            nx0 = load_in(tn * 32,      n, quad, edge_index, x4b, edge_attr, cursor);
            nx1 = load_in(tn * 32 + 16, n, quad, edge_index, x4b, edge_attr, cursor);
        }

        // B1 direct from registers
        BU t0, t1;
        t0.u[0] = cur0.w0; t0.u[1] = cur0.w1; t0.u[2] = cur0.w2; t0.u[3] = cur0.w3;
        t1.u[0] = cur1.w0; t1.u[1] = cur1.w1; t1.u[2] = cur1.w2; t1.u[3] = cur1.w3;
        short8 B1a = t0.s, B1b = t1.s;

        // ---- layer 1: [64ch] x K=32 ----
        unsigned U1a[4][2], U1b[4][2];
        #pragma unroll
        for (int t4 = 0; t4 < 4; t4++) {
            float4_ za = {0.f, 0.f, 0.f, 0.f}, zb = {0.f, 0.f, 0.f, 0.f};
            za = __builtin_amdgcn_mfma_f32_16x16x32_bf16(A1l[t4], B1a, za, 0, 0, 0);
            zb = __builtin_amdgcn_mfma_f32_16x16x32_bf16(A1l[t4], B1b, zb, 0, 0, 0);
            za = __builtin_amdgcn_mfma_f32_16x16x32_bf16(A1h[t4], B1a, za, 0, 0, 0);
            zb = __builtin_amdgcn_mfma_f32_16x16x32_bf16(A1h[t4], B1b, zb, 0, 0, 0);
            U1a[t4][0] = pkbf(fmaxf(za[0], 0.f), fmaxf(za[1], 0.f));
            U1a[t4][1] = pkbf(fmaxf(za[2], 0.f), fmaxf(za[3], 0.f));
            U1b[t4][0] = pkbf(fmaxf(zb[0], 0.f), fmaxf(zb[1], 0.f));
            U1b[t4][1] = pkbf(fmaxf(zb[2], 0.f), fmaxf(zb[3], 0.f));
        }
        // bias channel 50: block 3, m_local 2 (ch 50), handled via weight layout k50;
        // inject bias=1 at k=50: k50 -> chunk kc=1, quad_b=2, j=2 -> set in B2 after perm.

        short8 B2a0, B2a1, B2b0, B2b1;
        perm64(U1a, s0, s1, hi, B2a0, B2a1);
        perm64(U1b, s0, s1, hi, B2b0, B2b1);
        // k=50: kc=1, quad_b=(50>>3)&3=2, j=50&7=2 -> element 2 (low half of uint1)
        if (quad == 2) {
            BU fa, fb; fa.s = B2a1; fb.s = B2b1;
            fa.u[1] = (fa.u[1] & 0xFFFF0000u) | 0x3F80u;
            fb.u[1] = (fb.u[1] & 0xFFFF0000u) | 0x3F80u;
            B2a1 = fa.s; B2b1 = fb.s;
        }

        // ---- layer 2: [16ch] x K=64 ----
        float4_ a2a = {0.f, 0.f, 0.f, 0.f}, a2b = {0.f, 0.f, 0.f, 0.f};
        a2a = __builtin_amdgcn_mfma_f32_16x16x32_bf16(A2l[0], B2a0, a2a, 0, 0, 0);
        a2b = __builtin_amdgcn_mfma_f32_16x16x32_bf16(A2l[0], B2b0, a2b, 0, 0, 0);
        a2a = __builtin_amdgcn_mfma_f32_16x16x32_bf16(A2h[0], B2a0, a2a, 0, 0, 0);
        a2b = __builtin_amdgcn_mfma_f32_16x16x32_bf16(A2h[0], B2b0, a2b, 0, 0, 0);
        a2a = __builtin_amdgcn_mfma_f32_16x16x32_bf16(A2l[1], B2a1, a2a, 0, 0, 0);
        a2b = __builtin_amdgcn_mfma_f32_16x16x32_bf16(A2l[1], B2b1, a2b, 0, 0, 0);
        a2a = __builtin_amdgcn_mfma_f32_16x16x32_bf16(A2h[1], B2a1, a2a, 0, 0, 0);
        a2b = __builtin_amdgcn_mfma_f32_16x16x32_bf16(A2h[1], B2b1, a2b, 0, 0, 0);

        unsigned U2a[2] = { pkbf(a2a[0], a2a[1]), pkbf(a2a[2], a2a[3]) };
        unsigned U2b[2] = { pkbf(a2b[0], a2b[1]), pkbf(a2b[2], a2b[3]) };

        short8 B3a = perm16(U2a, s0, s1, quad, cur0.h0, cur0.h1);
        short8 B3b = perm16(U2b, s0, s1, quad, cur1.h0, cur1.h1);

        // ---- layer 3: [64ch] x K=32 ----
        unsigned U3a[4][2], U3b[4][2];
        #pragma unroll
        for (int t4 = 0; t4 < 4; t4++) {
            float4_ za = {0.f, 0.f, 0.f, 0.f}, zb = {0.f, 0.f, 0.f, 0.f};
            za = __builtin_amdgcn_mfma_f32_16x16x32_bf16(A3l[t4], B3a, za, 0, 0, 0);
            zb = __builtin_amdgcn_mfma_f32_16x16x32_bf16(A3l[t4], B3b, zb, 0, 0, 0);
            za = __builtin_amdgcn_mfma_f32_16x16x32_bf16(A3h[t4], B3a, za, 0, 0, 0);
            zb = __builtin_amdgcn_mfma_f32_16x16x32_bf16(A3h[t4], B3b, zb, 0, 0, 0);
            U3a[t4][0] = pkbf(fmaxf(za[0], 0.f), fmaxf(za[1], 0.f));
            U3a[t4][1] = pkbf(fmaxf(za[2], 0.f), fmaxf(za[3], 0.f));
            U3b[t4][0] = pkbf(fmaxf(zb[0], 0.f), fmaxf(zb[1], 0.f));
            U3b[t4][1] = pkbf(fmaxf(zb[2], 0.f), fmaxf(zb[3], 0.f));
        }

        short8 B4a0, B4a1, B4b0, B4b1;
        perm64(U3a, s0, s1, hi, B4a0, B4a1);
        perm64(U3b, s0, s1, hi, B4b0, B4b1);
        if (quad == 2) {
            BU fa, fb; fa.s = B4a1; fb.s = B4b1;
            fa.u[1] = (fa.u[1] & 0xFFFF0000u) | 0x3F80u;
            fb.u[1] = (fb.u[1] & 0xFFFF0000u) | 0x3F80u;
            B4a1 = fa.s; B4b1 = fb.s;
        }

        // ---- layer 4: [16ch] x K=64 ----
        float4_ ma = {0.f, 0.f, 0.f, 0.f}, mb = {0.f, 0.f, 0.f, 0.f};
        ma = __builtin_amdgcn_mfma_f32_16x16x32_bf16(A4l[0], B4a0, ma, 0, 0, 0);
        mb = __builtin_amdgcn_mfma_f32_16x16x32_bf16(A4l[0], B4b0, mb, 0, 0, 0);
        ma = __builtin_amdgcn_mfma_f32_16x16x32_bf16(A4h[0], B4a0, ma, 0, 0, 0);
        mb = __builtin_amdgcn_mfma_f32_16x16x32_bf16(A4h[0], B4b0, mb, 0, 0, 0);
        ma = __builtin_amdgcn_mfma_f32_16x16x32_bf16(A4l[1], B4a1, ma, 0, 0, 0);
        mb = __builtin_amdgcn_mfma_f32_16x16x32_bf16(A4l[1], B4b1, mb, 0, 0, 0);
        ma = __builtin_amdgcn_mfma_f32_16x16x32_bf16(A4h[1], B4a1, ma, 0, 0, 0);
        mb = __builtin_amdgcn_mfma_f32_16x16x32_bf16(A4h[1], B4b1, mb, 0, 0, 0);

        *(float4_*)(msg + (size_t)p0 * 16 + quad * 4) = ma;
        *(float4_*)(msg + (size_t)p1 * 16 + quad * 4) = mb;

        cur0 = nx0; cur1 = nx1; t = tn;
    }
}

// ---------- fused gather (CSR segment mean) + pool (sorted batch) ----------
__global__ __launch_bounds__(256) void gather_pool_kernel(
    const float* __restrict__ msg, const int* __restrict__ scanned,
    const int* __restrict__ bofs, const int* __restrict__ counts,
    const int* __restrict__ batch, float* __restrict__ gsum)
{
    __shared__ float acc[64 * 16];
    int n0 = blockIdx.x * 256;
    int n = n0 + threadIdx.x;

    float v[16];
    #pragma unroll
    for (int k = 0; k < 16; k++) v[k] = 0.0f;
    if (n < N_NODES) {
        int start = scanned[n] + bofs[n >> 10];
        int deg = counts[n];
        for (int j = 0; j < deg; j++) {
            const float4* mp = (const float4*)(msg + (size_t)(start + j) * 16);
            float4 b0 = mp[0], b1 = mp[1], b2 = mp[2], b3 = mp[3];
            v[0] += b0.x;  v[1] += b0.y;  v[2] += b0.z;  v[3] += b0.w;
            v[4] += b1.x;  v[5] += b1.y;  v[6] += b1.z;  v[7] += b1.w;
            v[8] += b2.x;  v[9] += b2.y;  v[10] += b2.z; v[11] += b2.w;
            v[12] += b3.x; v[13] += b3.y; v[14] += b3.z;
        }
        float inv = 1.0f / fmaxf((float)deg, 1.0f);
        #pragma unroll
        for (int k = 0; k < 15; k++) v[k] *= inv;
        v[15] = 1.0f;   // node count
    }

    int gmin = batch[n0];
    int gmax = batch[min(n0 + 255, N_NODES - 1)];
    int range = gmax - gmin + 1;
    if (range <= 64) {
        for (int t = threadIdx.x; t < range * 16; t += 256) acc[t] = 0.0f;
        __syncthreads();
        if (n < N_NODES) {
            int g = batch[n] - gmin;
            float* dst = &acc[g * 16];
            #pragma unroll
            for (int k = 0; k < 16; k++) atomicAdd(&dst[k], v[k]);
        }
        __syncthreads();
        for (int t = threadIdx.x; t < range * 16; t += 256) {
            float w = acc[t];
            if (w != 0.0f) atomicAdd(&gsum[(size_t)gmin * 16 + t], w);
        }
    } else {
        if (n < N_NODES) {
            int g = batch[n];
            float* dst = gsum + (size_t)g * 16;
            #pragma unroll
            for (int k = 0; k < 16; k++) atomicAdd(&dst[k], v[k]);
        }
    }
}

// ---------- head ----------
__global__ __launch_bounds__(512) void head_kernel(
    const float* __restrict__ gsum,
    const float* __restrict__ fc1w, const float* __restrict__ fc1b,
    const float* __restrict__ gamma, const float* __restrict__ beta,
    const float* __restrict__ fc2w, const float* __restrict__ fc2b,
    float* __restrict__ out)
{
    __shared__ float ssum[D5], ssq[D5], smu[D5], sistd[D5];
    int g = threadIdx.x;
    if (g < D5) { ssum[g] = 0.0f; ssq[g] = 0.0f; }
    __syncthreads();

    const float* src = gsum + (size_t)g * 16;
    float inv = 1.0f / fmaxf(src[15], 1.0f);
    float u[D3];
    #pragma unroll
    for (int k = 0; k < D3; k++) u[k] = src[k] * inv;

    float h[D5];
    #pragma unroll
    for (int c = 0; c < D5; c++) h[c] = fc1b[c];
    #pragma unroll
    for (int k = 0; k < D3; k++) {
        float v = u[k];
        #pragma unroll
        for (int c = 0; c < D5; c++) h[c] = fmaf(v, fc1w[k * D5 + c], h[c]);
    }

    int lane = threadIdx.x & 63;
    #pragma unroll
    for (int c = 0; c < D5; c++) {
        float v = h[c];
        float v2 = v * v;
        #pragma unroll
        for (int off = 32; off >= 1; off >>= 1) {
            v  += __shfl_xor(v,  off);
            v2 += __shfl_xor(v2, off);
        }
        if (lane == 0) { atomicAdd(&ssum[c], v); atomicAdd(&ssq[c], v2); }
    }
    __syncthreads();
    if (g < D5) {
        float mu = ssum[g] * (1.0f / NUM_GRAPHS);
        float var = ssq[g] * (1.0f / NUM_GRAPHS) - mu * mu;
        smu[g] = mu;
        sistd[g] = rsqrtf(var + BN_EPS);
    }
    __syncthreads();

    float hn[D5];
    #pragma unroll
    for (int c = 0; c < D5; c++) {
        float v = gamma[c] * (h[c] - smu[c]) * sistd[c] + beta[c];
        hn[c] = fmaxf(v, 0.0f);
    }

    float lg[NCLS];
    #pragma unroll
    for (int j = 0; j < NCLS; j++) lg[j] = fc2b[j];
    #pragma unroll
    for (int c = 0; c < D5; c++) {
        float v = hn[c];
        #pragma unroll
        for (int j = 0; j < NCLS; j++) lg[j] = fmaf(v, fc2w[c * NCLS + j], lg[j]);
    }

    float m = lg[0];
    #pragma unroll
    for (int j = 1; j < NCLS; j++) m = fmaxf(m, lg[j]);
    float se = 0.0f;
    #pragma unroll
    for (int j = 0; j < NCLS; j++) se += expf(lg[j] - m);
    float lse = logf(se);
    #pragma unroll
    for (int j = 0; j < NCLS; j++) out[g * NCLS + j] = lg[j] - m - lse;
}

extern "C" void kernel_launch(void* const* d_in, const int* in_sizes, int n_in,
                              void* d_out, int out_size, void* d_ws, size_t ws_size,
                              hipStream_t stream) {
    const float* x         = (const float*)d_in[0];
    const float* edge_attr = (const float*)d_in[1];
    const float* ew1  = (const float*)d_in[2];
    const float* eb1  = (const float*)d_in[3];
    const float* ew2  = (const float*)d_in[4];
    const float* eb2  = (const float*)d_in[5];
    const float* nw1  = (const float*)d_in[6];
    const float* nb1  = (const float*)d_in[7];
    const float* nw2  = (const float*)d_in[8];
    const float* nb2  = (const float*)d_in[9];
    const float* fc1w = (const float*)d_in[10];
    const float* fc1b = (const float*)d_in[11];
    const float* gamma= (const float*)d_in[12];
    const float* beta = (const float*)d_in[13];
    const float* fc2w = (const float*)d_in[14];
    const float* fc2b = (const float*)d_in[15];
    const int* edge_index = (const int*)d_in[16];
    const int* batch      = (const int*)d_in[17];

    // workspace layout
    char* p = (char*)d_ws;
    float* msg = (float*)p;            p += (size_t)N_EDGES * 16 * sizeof(float);  // 102.4 MB
    int* counts  = (int*)p;            p += (size_t)N_NODES * sizeof(int);
    int* scanned = (int*)p;            p += (size_t)N_NODES * sizeof(int);
    int* cursor  = (int*)p;            p += (size_t)N_NODES * sizeof(int);
    int* bsums   = (int*)p;            p += 128 * sizeof(int);
    int* bofs    = (int*)p;            p += 128 * sizeof(int);
    ushort4* x4b = (ushort4*)p;        p += (size_t)N_NODES * sizeof(ushort4);     // 0.8 MB
    float* gsum  = (float*)p;          p += (size_t)NUM_GRAPHS * 16 * sizeof(float);
    unsigned short* wh = (unsigned short*)p; p += W_TOTAL * sizeof(unsigned short);
    unsigned short* wl = (unsigned short*)p; p += W_TOTAL * sizeof(unsigned short);

    hipMemsetAsync(counts, 0, (size_t)N_NODES * sizeof(int), stream);
    hipMemsetAsync(gsum, 0, (size_t)NUM_GRAPHS * 16 * sizeof(float), stream);

    int egrid = (N_EDGES + 255) / 256;
    int ngrid = (N_NODES + 255) / 256;

    prep_kernel<<<egrid, 256, 0, stream>>>(
        ew1, eb1, ew2, eb2, nw1, nb1, nw2, nb2, wh, wl,
        x, x4b, edge_index, counts);
    scan1_kernel<<<NBLK1, 1024, 0, stream>>>(counts, scanned, bsums);
    scan2_kernel<<<1, 128, 0, stream>>>(bsums, bofs);
    scan3_kernel<<<ngrid, 256, 0, stream>>>(scanned, bofs, cursor);
    edge_mfma_kernel<<<EDGE_BLOCKS, 256, 0, stream>>>(
        wh, wl, x4b, edge_attr, edge_index, cursor, msg);
    gather_pool_kernel<<<ngrid, 256, 0, stream>>>(
        msg, scanned, bofs, counts, batch, gsum);
    head_kernel<<<1, 512, 0, stream>>>(
        gsum, fc1w, fc1b, gamma, beta, fc2w, fc2b, (float*)d_out);
}